// Round 3
// baseline (10411.551 us; speedup 1.0000x reference)
//
#include <hip/hip_runtime.h>
#include <math.h>

// SRHDR fused windowed-attention block, MI355X round 3.
// R3 change: __launch_bounds__(256,2)->(256,1). R2 spilled ~60 VGPRs (cap 128 with
// 128 f32 of persistent state) -> 760MB scratch traffic, VALUBusy 8.4%. One lever.

typedef unsigned short u16;
typedef unsigned int u32;

#define DEVINL __device__ __forceinline__

DEVINL float blo(u32 u){ return __uint_as_float(u << 16); }
DEVINL float bhi(u32 u){ return __uint_as_float(u & 0xffff0000u); }
DEVINL float b2f(u16 h){ return __uint_as_float(((u32)h) << 16); }
DEVINL u16 f2b(float f){
  u32 u = __float_as_uint(f);
  return (u16)((u + 0x7fffu + ((u >> 16) & 1u)) >> 16);   // RNE
}
DEVINL float gelu_ex(float x){ return 0.5f * x * (1.0f + erff(x * 0.7071067811865476f)); }

#define UNP8(q, B, u) \
  q[(B)+0]=blo(u.x); q[(B)+1]=bhi(u.x); q[(B)+2]=blo(u.y); q[(B)+3]=bhi(u.y); \
  q[(B)+4]=blo(u.z); q[(B)+5]=bhi(u.z); q[(B)+6]=blo(u.w); q[(B)+7]=bhi(u.w);

#define DOT8(a, u, q, B) \
  a = fmaf(q[(B)+0], blo(u.x), a); a = fmaf(q[(B)+1], bhi(u.x), a); \
  a = fmaf(q[(B)+2], blo(u.y), a); a = fmaf(q[(B)+3], bhi(u.y), a); \
  a = fmaf(q[(B)+4], blo(u.z), a); a = fmaf(q[(B)+5], bhi(u.z), a); \
  a = fmaf(q[(B)+6], blo(u.w), a); a = fmaf(q[(B)+7], bhi(u.w), a);

#define AXPY8(o, B, pm, u) \
  o[(B)+0] = fmaf(pm, blo(u.x), o[(B)+0]); o[(B)+1] = fmaf(pm, bhi(u.x), o[(B)+1]); \
  o[(B)+2] = fmaf(pm, blo(u.y), o[(B)+2]); o[(B)+3] = fmaf(pm, bhi(u.y), o[(B)+3]); \
  o[(B)+4] = fmaf(pm, blo(u.z), o[(B)+4]); o[(B)+5] = fmaf(pm, bhi(u.z), o[(B)+5]); \
  o[(B)+6] = fmaf(pm, blo(u.w), o[(B)+6]); o[(B)+7] = fmaf(pm, bhi(u.w), o[(B)+7]);

// NOTE: param named W (capital) — member access .w must not collide with a macro param.
#define FMA4A(acc, B, a, W) \
  acc[(B)+0] = fmaf(a, W.x, acc[(B)+0]); acc[(B)+1] = fmaf(a, W.y, acc[(B)+1]); \
  acc[(B)+2] = fmaf(a, W.z, acc[(B)+2]); acc[(B)+3] = fmaf(a, W.w, acc[(B)+3]);

// projection: dst[h][n][c] = sum_k XW[e][n][k] * Wg[k][colbase + h*32 + c] * scale  (bf16 store)
DEVINL void proj(u16* __restrict__ dst, const float* __restrict__ XW, int e,
                 const float* __restrict__ Wg, int colbase, float scale, int t)
{
  const int h = t >> 6, c = t & 31, nh2 = (t >> 5) & 1;
  const int col = colbase + (h << 5) + c;
  float wr[32];
  #pragma unroll
  for (int k = 0; k < 32; ++k) wr[k] = Wg[k * 384 + col] * scale;
  const float* src = XW + (e << 11);
  u16* d = dst + (h << 11) + c;
  const int n0 = nh2 << 5;
  for (int ni = 0; ni < 32; ++ni){
    const int n = n0 + ni;
    const float4* row = (const float4*)(src + (n << 5));
    float acc = 0.f;
    #pragma unroll
    for (int q = 0; q < 8; ++q){
      float4 r = row[q];
      acc = fmaf(r.x, wr[4*q+0], acc);
      acc = fmaf(r.y, wr[4*q+1], acc);
      acc = fmaf(r.z, wr[4*q+2], acc);
      acc = fmaf(r.w, wr[4*q+3], acc);
    }
    d[n << 5] = f2b(acc);
  }
}

// scores: wave h, lane n:  sc[m] (+)= sum_c q[h][n][c] * k[h][m][c]
template<bool ACC>
DEVINL void score64(const u16* __restrict__ qb, const u16* __restrict__ kb,
                    float* sc, int t)
{
  const int h = t >> 6, n = t & 63;
  float q[32];
  {
    const uint4* qr = (const uint4*)(qb + (h << 11) + (n << 5));
    uint4 u0 = qr[0], u1 = qr[1], u2 = qr[2], u3 = qr[3];
    UNP8(q, 0, u0); UNP8(q, 8, u1); UNP8(q, 16, u2); UNP8(q, 24, u3);
  }
  const u16* kbase = kb + (h << 11);
  #pragma unroll
  for (int m = 0; m < 64; ++m){
    const uint4* kr = (const uint4*)(kbase + (m << 5));
    uint4 u0 = kr[0], u1 = kr[1], u2 = kr[2], u3 = kr[3];
    float a = 0.f;
    DOT8(a, u0, q, 0); DOT8(a, u1, q, 8); DOT8(a, u2, q, 16); DOT8(a, u3, q, 24);
    if (ACC) sc[m] += a; else sc[m] = a;
  }
}

DEVINL float softmax64(float* sc){
  float mx = sc[0];
  #pragma unroll
  for (int m = 1; m < 64; ++m) mx = fmaxf(mx, sc[m]);
  float sum = 0.f;
  #pragma unroll
  for (int m = 0; m < 64; ++m){ const float p = __expf(sc[m] - mx); sc[m] = p; sum += p; }
  return 1.f / sum;
}

// PV: out[h][n][c] = rinv * sum_m p[m] * v[h][m][c]; store TRANSPOSED oc[h][c][n]
DEVINL void pv_store(const u16* __restrict__ vb, const float* p, float rinv,
                     u16* __restrict__ oc, int t)
{
  const int h = t >> 6, n = t & 63;
  float o[32];
  #pragma unroll
  for (int i = 0; i < 32; ++i) o[i] = 0.f;
  const u16* vbase = vb + (h << 11);
  #pragma unroll
  for (int m = 0; m < 64; ++m){
    const uint4* vr = (const uint4*)(vbase + (m << 5));
    uint4 u0 = vr[0], u1 = vr[1], u2 = vr[2], u3 = vr[3];
    const float pm = p[m];
    AXPY8(o, 0, pm, u0); AXPY8(o, 8, pm, u1); AXPY8(o, 16, pm, u2); AXPY8(o, 24, pm, u3);
  }
  u16* ob = oc + (h << 11) + n;
  #pragma unroll
  for (int c = 0; c < 32; ++c) ob[c << 6] = f2b(o[c] * rinv);
}

// streamed MLP1 accumulation: acc[n][j] += oc[h4][k][n] * W[rowbase + h4*128 + k][j]
DEVINL void mlp_acc(const u16* __restrict__ oc, int rowbase,
                    const float* __restrict__ W1, const float* __restrict__ W2g,
                    float* a1, float* a2, int t)
{
  const int n = t >> 2, jb = t & 3;
  const int joff = jb << 5;
  for (int h4 = 0; h4 < 4; ++h4){
    const u16* op = oc + (h4 << 11) + n;
    const float* w1b = W1  + (rowbase + (h4 << 7)) * 128 + joff;
    const float* w2b = W2g + (rowbase + (h4 << 7)) * 128 + joff;
    for (int k = 0; k < 32; ++k){
      const float a = b2f(op[k << 6]);
      const float4* w1 = (const float4*)(w1b + k * 128);
      const float4* w2 = (const float4*)(w2b + k * 128);
      #pragma unroll
      for (int q = 0; q < 8; ++q){ float4 wa = w1[q]; FMA4A(a1, 4*q, a, wa); }
      #pragma unroll
      for (int q = 0; q < 8; ++q){ float4 wb = w2[q]; FMA4A(a2, 4*q, a, wb); }
    }
  }
}

__global__ __launch_bounds__(256, 1)
void k_win(const float* __restrict__ X,
           const float* __restrict__ Wea, const float* __restrict__ Wsa,
           const float* __restrict__ g1, const float* __restrict__ b1,
           const float* __restrict__ rpb,
           const float* __restrict__ W11, const float* __restrict__ B11,
           const float* __restrict__ W12, const float* __restrict__ B12,
           const float* __restrict__ W2,  const float* __restrict__ B2v,
           float* __restrict__ OUT)
{
  __shared__ __align__(16) float XW[4 * 64 * 32];     // 32KB  LN'd window, [e][n][cc]
  __shared__ __align__(16) u16 SM[3 * 4 * 64 * 32];   // 48KB  three bf16 stage buffers
  u16* Bs0 = SM;
  u16* Bs1 = SM + 8192;
  u16* Bs2 = SM + 16384;
  float* H1 = (float*)SM;                             // 32KB alias (used after attention phases)

  const int t = threadIdx.x;
  const int win = blockIdx.x;
  const int ihh = win / 24, iww = win % 24;
  const float SC = 0.17677669529663687f;              // 32^-0.5

  // ---------- gather + LN1 ----------
  {
    const int e = t >> 6, n = t & 63;
    const int cch = n >> 1, hf = n & 1;
    const float* base = X + (e * 32 + cch) * 36864 + (ihh * 8) * 192 + iww * 8;
    float v[32];
    #pragma unroll
    for (int r = 0; r < 4; ++r){
      const float4* p4 = (const float4*)(base + (hf * 4 + r) * 192);
      float4 a = p4[0], b = p4[1];
      v[r*8+0]=a.x; v[r*8+1]=a.y; v[r*8+2]=a.z; v[r*8+3]=a.w;
      v[r*8+4]=b.x; v[r*8+5]=b.y; v[r*8+6]=b.z; v[r*8+7]=b.w;
    }
    float s = 0.f;
    #pragma unroll
    for (int i = 0; i < 32; ++i) s += v[i];
    const float mean = s * 0.03125f;
    float vs = 0.f;
    #pragma unroll
    for (int i = 0; i < 32; ++i){ const float d = v[i] - mean; vs = fmaf(d, d, vs); }
    const float rstd = rsqrtf(vs * 0.03125f + 1e-5f);
    float* dst = XW + (e << 11) + (n << 5);
    #pragma unroll
    for (int i = 0; i < 32; ++i) dst[i] = (v[i] - mean) * rstd * g1[i] + b1[i];
  }
  __syncthreads();

  float acc11[32], acc12[32];
  #pragma unroll
  for (int i = 0; i < 32; ++i){ acc11[i] = 0.f; acc12[i] = 0.f; }
  float sc[64];

  // ---------- SA (head dim 128 = 4 chunks of 32 over exposures; xw WITHOUT POS) ----------
  #pragma unroll
  for (int m = 0; m < 64; ++m) sc[m] = 0.f;
  for (int e = 0; e < 4; ++e){
    proj(Bs0, XW, e, Wsa, 0,   SC,  t);   // q chunk (scale folded)
    proj(Bs1, XW, e, Wsa, 128, 1.f, t);   // k chunk
    __syncthreads();
    score64<true>(Bs0, Bs1, sc, t);
    __syncthreads();
  }
  {  // swin relative-position bias: rpb[((dy+7)*15 + dx+7)*4 + h]
    const int h = t >> 6, n = t & 63;
    const int by = (n >> 3) + 7, bx = (n & 7) + 7;
    #pragma unroll
    for (int m = 0; m < 64; ++m){
      const int idx = (by - (m >> 3)) * 15 + (bx - (m & 7));
      sc[m] += rpb[idx * 4 + h];
    }
  }
  {
    const float rinv = softmax64(sc);
    for (int e = 0; e < 4; ++e){
      proj(Bs1, XW, e, Wsa, 256, 1.f, t); // v chunk
      __syncthreads();
      pv_store(Bs1, sc, rinv, Bs2, t);
      __syncthreads();
      mlp_acc(Bs2, (e << 5), W11, W12, acc11, acc12, t);  // feat rows h*128 + e*32 + k
      __syncthreads();
    }
  }

  // ---------- XW += POS (DETR sine enc, computed on the fly) ----------
  {
    const int n = t & 63;
    const int e = t >> 6;
    const float ye = (float)((n >> 3) + 1) * 0.7853980652f;  // 2*pi/(8+1e-6)
    const float xe = (float)((n & 7) + 1) * 0.7853980652f;
    float* row = XW + (e << 11) + (n << 5);
    #pragma unroll
    for (int cc = 0; cc < 32; ++cc){
      const int j = (cc & 15) >> 1;
      const float dimv = __expf(1.1512925465f * (float)j); // 10000^(j/8)
      const float arg = ((cc < 16) ? ye : xe) / dimv;
      row[cc] += (cc & 1) ? __cosf(arg) : __sinf(arg);
    }
  }
  __syncthreads();

  // ---------- EA1: attn(q0, k_e, v_e), feat rows 512 + h*128 + e*32 ----------
  proj(Bs0, XW, 0, Wea, 0, SC, t);        // q0, persists
  __syncthreads();
  for (int e = 0; e < 4; ++e){
    proj(Bs1, XW, e, Wea, 128, 1.f, t);   // k_e
    __syncthreads();
    score64<false>(Bs0, Bs1, sc, t);
    const float r2 = softmax64(sc);
    __syncthreads();
    proj(Bs1, XW, e, Wea, 256, 1.f, t);   // v_e
    __syncthreads();
    pv_store(Bs1, sc, r2, Bs2, t);
    __syncthreads();
    mlp_acc(Bs2, 512 + (e << 5), W11, W12, acc11, acc12, t);
    __syncthreads();
  }

  // ---------- EA2: attn(q_e, k0, v0), feat rows 1024 + h*128 + e*32 ----------
  proj(Bs0, XW, 0, Wea, 128, 1.f, t);     // k0, persists
  proj(Bs1, XW, 0, Wea, 256, 1.f, t);     // v0, persists
  __syncthreads();
  for (int e = 0; e < 4; ++e){
    proj(Bs2, XW, e, Wea, 0, SC, t);      // q_e
    __syncthreads();
    score64<false>(Bs2, Bs0, sc, t);
    const float r2 = softmax64(sc);
    __syncthreads();                      // q reads done before Bs2 reused as OC
    pv_store(Bs1, sc, r2, Bs2, t);
    __syncthreads();
    mlp_acc(Bs2, 1024 + (e << 5), W11, W12, acc11, acc12, t);
    __syncthreads();
  }

  // ---------- GEGLU gate -> H1 ----------
  {
    const int n = t >> 2, jb = t & 3;
    float* h1p = H1 + n * 128 + (jb << 5);
    #pragma unroll
    for (int i = 0; i < 32; ++i){
      const float vg = acc11[i] + B11[(jb << 5) + i];
      const float vl = acc12[i] + B12[(jb << 5) + i];
      h1p[i] = gelu_ex(vg) * vl;
    }
  }
  __syncthreads();

  // ---------- fc2 + faithful un-window + residual ----------
  {
    const int n = t >> 2, db = t & 3;
    float o[32];
    #pragma unroll
    for (int i = 0; i < 32; ++i) o[i] = B2v[(db << 5) + i];
    const float* h1p = H1 + n * 128;
    for (int j = 0; j < 128; ++j){
      const float hj = h1p[j];
      const float4* wr = (const float4*)(W2 + j * 128 + (db << 5));
      #pragma unroll
      for (int q = 0; q < 8; ++q){ float4 w4 = wr[q]; FMA4A(o, 4*q, hj, w4); }
    }
    const int hh = (n >> 3) * 24 + ihh;
    const int ww = (n & 7) * 24 + iww;
    const int pix = hh * 192 + ww;
    const float* xin = X + (db << 5) * 36864 + pix;
    float* op = OUT + (db << 5) * 36864 + pix;
    #pragma unroll
    for (int i = 0; i < 32; ++i) op[i * 36864] = o[i] + xin[i * 36864];
  }
}

// ---------- K2: LN2 + GEGLU MLP2 + residual, in-place on d_out ----------
__global__ __launch_bounds__(256, 1)
void k_mlp2(float* __restrict__ IO,
            const float* __restrict__ g2, const float* __restrict__ b2,
            const float* __restrict__ W11, const float* __restrict__ B11,
            const float* __restrict__ W12, const float* __restrict__ B12,
            const float* __restrict__ W2,  const float* __restrict__ B2v)
{
  __shared__ __align__(16) float T[128 * 64];  // x1 tile [f][pix]
  __shared__ __align__(16) float U[128 * 64];  // normalized, then hidden
  const int t = threadIdx.x;
  const int p0 = blockIdx.x << 6;

  #pragma unroll
  for (int i = 0; i < 32; ++i){
    const int idx = (i << 8) + t;
    const int f = idx >> 6, pix = idx & 63;
    T[(f << 6) + pix] = IO[f * 36864 + p0 + pix];
  }
  __syncthreads();

  const int pix = t & 63, quad = t >> 6;
  {
    float sum = 0.f, ss = 0.f;
    for (int f = 0; f < 128; ++f){ const float v = T[(f << 6) + pix]; sum += v; ss = fmaf(v, v, ss); }
    const float mean = sum * 0.0078125f;
    const float var = ss * 0.0078125f - mean * mean;
    const float rstd = rsqrtf(var + 1e-5f);
    const int f0 = quad << 5;
    for (int f = f0; f < f0 + 32; ++f)
      U[(f << 6) + pix] = (T[(f << 6) + pix] - mean) * rstd * g2[f] + b2[f];
  }
  __syncthreads();

  float a1[32], a2[32];
  #pragma unroll
  for (int i = 0; i < 32; ++i){ a1[i] = 0.f; a2[i] = 0.f; }
  const int joff = quad << 5;
  for (int f = 0; f < 128; ++f){
    const float xv = U[(f << 6) + pix];
    const float4* w1 = (const float4*)(W11 + f * 128 + joff);
    const float4* w2 = (const float4*)(W12 + f * 128 + joff);
    #pragma unroll
    for (int q = 0; q < 8; ++q){ float4 wa = w1[q]; FMA4A(a1, 4*q, xv, wa); }
    #pragma unroll
    for (int q = 0; q < 8; ++q){ float4 wb = w2[q]; FMA4A(a2, 4*q, xv, wb); }
  }
  float hid[32];
  #pragma unroll
  for (int i = 0; i < 32; ++i)
    hid[i] = gelu_ex(a1[i] + B11[joff + i]) * (a2[i] + B12[joff + i]);
  __syncthreads();
  #pragma unroll
  for (int i = 0; i < 32; ++i) U[((joff + i) << 6) + pix] = hid[i];
  __syncthreads();

  float o[32];
  #pragma unroll
  for (int i = 0; i < 32; ++i) o[i] = B2v[joff + i];
  for (int j = 0; j < 128; ++j){
    const float u = U[(j << 6) + pix];
    const float4* wr = (const float4*)(W2 + j * 128 + joff);
    #pragma unroll
    for (int q = 0; q < 8; ++q){ float4 w4 = wr[q]; FMA4A(o, 4*q, u, w4); }
  }
  #pragma unroll
  for (int i = 0; i < 32; ++i){
    const int f = joff + i;
    IO[f * 36864 + p0 + pix] = T[(f << 6) + pix] + o[i];
  }
}

extern "C" void kernel_launch(void* const* d_in, const int* in_sizes, int n_in,
                              void* d_out, int out_size, void* d_ws, size_t ws_size,
                              hipStream_t stream)
{
  (void)in_sizes; (void)n_in; (void)out_size; (void)d_ws; (void)ws_size;
  const float* X    = (const float*)d_in[0];
  const float* Wea  = (const float*)d_in[1];
  const float* Wsa  = (const float*)d_in[2];
  const float* g1   = (const float*)d_in[3];
  const float* b1   = (const float*)d_in[4];
  const float* g2   = (const float*)d_in[5];
  const float* b2   = (const float*)d_in[6];
  const float* rpb  = (const float*)d_in[7];
  const float* W11  = (const float*)d_in[8];
  const float* B11  = (const float*)d_in[9];
  const float* W12  = (const float*)d_in[10];
  const float* B12  = (const float*)d_in[11];
  const float* W2   = (const float*)d_in[12];
  const float* B2v  = (const float*)d_in[13];
  const float* m11  = (const float*)d_in[14];
  const float* mb11 = (const float*)d_in[15];
  const float* m12  = (const float*)d_in[16];
  const float* mb12 = (const float*)d_in[17];
  const float* m2w  = (const float*)d_in[18];
  const float* mb2  = (const float*)d_in[19];
  float* OUT = (float*)d_out;

  k_win<<<dim3(576), dim3(256), 0, stream>>>(X, Wea, Wsa, g1, b1, rpb,
                                             W11, B11, W12, B12, W2, B2v, OUT);
  k_mlp2<<<dim3(576), dim3(256), 0, stream>>>(OUT, g2, b2, m11, mb11, m12, mb12, m2w, mb2);
}

// Round 4
// 9995.217 us; speedup vs baseline: 1.0417x; 1.0417x over previous
//
#include <hip/hip_runtime.h>
#include <math.h>

// SRHDR fused windowed-attention block, MI355X round 4.
// R4: kill register spills structurally. Scores become transient: softmax -> P (bf16,
// packed u32 pairs) in LDS; each lane re-reads only its own column (no cross-lane hazard).
// XW demoted to bf16. LDS = 16+16+16+32 = 80KB exactly -> 2 blocks/CU. Peak live regs ~200.

typedef unsigned short u16;
typedef unsigned int u32;

#define DEVINL __device__ __forceinline__

DEVINL float blo(u32 u){ return __uint_as_float(u << 16); }
DEVINL float bhi(u32 u){ return __uint_as_float(u & 0xffff0000u); }
DEVINL float b2f(u16 h){ return __uint_as_float(((u32)h) << 16); }
DEVINL u16 f2b(float f){
  u32 u = __float_as_uint(f);
  return (u16)((u + 0x7fffu + ((u >> 16) & 1u)) >> 16);   // RNE
}
DEVINL float gelu_ex(float x){ return 0.5f * x * (1.0f + erff(x * 0.7071067811865476f)); }

#define UNP8(q, B, u) \
  q[(B)+0]=blo(u.x); q[(B)+1]=bhi(u.x); q[(B)+2]=blo(u.y); q[(B)+3]=bhi(u.y); \
  q[(B)+4]=blo(u.z); q[(B)+5]=bhi(u.z); q[(B)+6]=blo(u.w); q[(B)+7]=bhi(u.w);

#define DOT8(a, u, q, B) \
  a = fmaf(q[(B)+0], blo(u.x), a); a = fmaf(q[(B)+1], bhi(u.x), a); \
  a = fmaf(q[(B)+2], blo(u.y), a); a = fmaf(q[(B)+3], bhi(u.y), a); \
  a = fmaf(q[(B)+4], blo(u.z), a); a = fmaf(q[(B)+5], bhi(u.z), a); \
  a = fmaf(q[(B)+6], blo(u.w), a); a = fmaf(q[(B)+7], bhi(u.w), a);

#define AXPY8(o, B, pm, u) \
  o[(B)+0] = fmaf(pm, blo(u.x), o[(B)+0]); o[(B)+1] = fmaf(pm, bhi(u.x), o[(B)+1]); \
  o[(B)+2] = fmaf(pm, blo(u.y), o[(B)+2]); o[(B)+3] = fmaf(pm, bhi(u.y), o[(B)+3]); \
  o[(B)+4] = fmaf(pm, blo(u.z), o[(B)+4]); o[(B)+5] = fmaf(pm, bhi(u.z), o[(B)+5]); \
  o[(B)+6] = fmaf(pm, blo(u.w), o[(B)+6]); o[(B)+7] = fmaf(pm, bhi(u.w), o[(B)+7]);

// NOTE: param named W (capital) — member access .w must not collide with a macro param.
#define FMA4A(acc, B, a, W) \
  acc[(B)+0] = fmaf(a, W.x, acc[(B)+0]); acc[(B)+1] = fmaf(a, W.y, acc[(B)+1]); \
  acc[(B)+2] = fmaf(a, W.z, acc[(B)+2]); acc[(B)+3] = fmaf(a, W.w, acc[(B)+3]);

// projection: dst[h][n][c] = sum_k XWb[e][n][k] * Wg[k][colbase + h*32 + c] * scale (bf16 in/out)
DEVINL void proj(u16* __restrict__ dst, const u16* __restrict__ XWb, int e,
                 const float* __restrict__ Wg, int colbase, float scale, int t)
{
  const int h = t >> 6, c = t & 31, nh2 = (t >> 5) & 1;
  const int col = colbase + (h << 5) + c;
  float wr[32];
  #pragma unroll
  for (int k = 0; k < 32; ++k) wr[k] = Wg[k * 384 + col] * scale;
  const u16* src = XWb + (e << 11);
  u16* d = dst + (h << 11) + c;
  const int n0 = nh2 << 5;
  for (int ni = 0; ni < 32; ++ni){
    const int n = n0 + ni;
    const uint4* row = (const uint4*)(src + (n << 5));
    uint4 u0 = row[0], u1 = row[1], u2 = row[2], u3 = row[3];
    float a = 0.f;
    DOT8(a, u0, wr, 0); DOT8(a, u1, wr, 8); DOT8(a, u2, wr, 16); DOT8(a, u3, wr, 24);
    d[n << 5] = f2b(a);
  }
}

// load this thread's (h,n) 32-wide bf16 row into f32 regs
DEVINL void load_row(const u16* __restrict__ buf, int t, float q[32]){
  const int h = t >> 6, n = t & 63;
  const uint4* r = (const uint4*)(buf + (h << 11) + (n << 5));
  uint4 u0 = r[0], u1 = r[1], u2 = r[2], u3 = r[3];
  UNP8(q, 0, u0); UNP8(q, 8, u1); UNP8(q, 16, u2); UNP8(q, 24, u3);
}

// scores: wave h, lane n: sc[m] (+)= sum_c q[c] * k[h][m][c]
template<bool ACC>
DEVINL void score_regq(const float* __restrict__ q, const u16* __restrict__ kb,
                       float* sc, int t)
{
  const int h = t >> 6;
  const u16* kbase = kb + (h << 11);
  #pragma unroll 8
  for (int m = 0; m < 64; ++m){
    const uint4* kr = (const uint4*)(kbase + (m << 5));
    uint4 u0 = kr[0], u1 = kr[1], u2 = kr[2], u3 = kr[3];
    float a = 0.f;
    DOT8(a, u0, q, 0); DOT8(a, u1, q, 8); DOT8(a, u2, q, 16); DOT8(a, u3, q, 24);
    if (ACC) sc[m] += a; else sc[m] = a;
  }
}

// softmax over sc[64], fold 1/sum, write P packed: Ps[h][m2][n] = (bf16(p[2m2+1])<<16)|bf16(p[2m2])
DEVINL void softmax_P(float* sc, u32* __restrict__ Ps, int t){
  const int h = t >> 6, n = t & 63;
  float mx = sc[0];
  #pragma unroll
  for (int m = 1; m < 64; ++m) mx = fmaxf(mx, sc[m]);
  float sum = 0.f;
  #pragma unroll
  for (int m = 0; m < 64; ++m){ const float p = __expf(sc[m] - mx); sc[m] = p; sum += p; }
  const float rinv = 1.f / sum;
  u32* pb = Ps + (h << 11) + n;
  #pragma unroll
  for (int m2 = 0; m2 < 32; ++m2){
    const u32 lo = f2b(sc[2*m2]   * rinv);
    const u32 hi = f2b(sc[2*m2+1] * rinv);
    pb[m2 << 6] = lo | (hi << 16);
  }
}

// PV: out[h][n][c] = sum_m P[h][n][m] * v[h][m][c]; lane reads back its own P column.
// store TRANSPOSED oc[h][c][n] (mlp_acc-friendly)
DEVINL void pv_lds(const u32* __restrict__ Ps, const u16* __restrict__ vb,
                   u16* __restrict__ oc, int t)
{
  const int h = t >> 6, n = t & 63;
  float o[32];
  #pragma unroll
  for (int i = 0; i < 32; ++i) o[i] = 0.f;
  const u16* vbase = vb + (h << 11);
  const u32* pb = Ps + (h << 11) + n;
  #pragma unroll 8
  for (int m2 = 0; m2 < 32; ++m2){
    const u32 pp = pb[m2 << 6];
    const float p0 = blo(pp), p1 = bhi(pp);
    const uint4* v0r = (const uint4*)(vbase + ((2*m2) << 5));
    const uint4* v1r = (const uint4*)(vbase + ((2*m2+1) << 5));
    uint4 a0 = v0r[0], a1 = v0r[1], a2 = v0r[2], a3 = v0r[3];
    AXPY8(o, 0, p0, a0); AXPY8(o, 8, p0, a1); AXPY8(o, 16, p0, a2); AXPY8(o, 24, p0, a3);
    uint4 b0 = v1r[0], b1 = v1r[1], b2 = v1r[2], b3 = v1r[3];
    AXPY8(o, 0, p1, b0); AXPY8(o, 8, p1, b1); AXPY8(o, 16, p1, b2); AXPY8(o, 24, p1, b3);
  }
  u16* ob = oc + (h << 11) + n;
  #pragma unroll
  for (int c = 0; c < 32; ++c) ob[c << 6] = f2b(o[c]);
}

// streamed MLP1 accumulation: acc[n][j] += oc[h4][k][n] * W[rowbase + h4*128 + k][j]
DEVINL void mlp_acc(const u16* __restrict__ oc, int rowbase,
                    const float* __restrict__ W1, const float* __restrict__ W2g,
                    float* a1, float* a2, int t)
{
  const int n = t >> 2, jb = t & 3;
  const int joff = jb << 5;
  for (int h4 = 0; h4 < 4; ++h4){
    const u16* op = oc + (h4 << 11) + n;
    const float* w1b = W1  + (rowbase + (h4 << 7)) * 128 + joff;
    const float* w2b = W2g + (rowbase + (h4 << 7)) * 128 + joff;
    for (int k = 0; k < 32; ++k){
      const float a = b2f(op[k << 6]);
      const float4* w1 = (const float4*)(w1b + k * 128);
      const float4* w2 = (const float4*)(w2b + k * 128);
      #pragma unroll
      for (int q = 0; q < 8; ++q){ float4 wa = w1[q]; FMA4A(a1, 4*q, a, wa); }
      #pragma unroll
      for (int q = 0; q < 8; ++q){ float4 wb = w2[q]; FMA4A(a2, 4*q, a, wb); }
    }
  }
}

__global__ __launch_bounds__(256, 1)
void k_win(const float* __restrict__ X,
           const float* __restrict__ Wea, const float* __restrict__ Wsa,
           const float* __restrict__ g1, const float* __restrict__ b1,
           const float* __restrict__ rpb,
           const float* __restrict__ W11, const float* __restrict__ B11,
           const float* __restrict__ W12, const float* __restrict__ B12,
           const float* __restrict__ W2,  const float* __restrict__ B2v,
           float* __restrict__ OUT)
{
  __shared__ __align__(16) u16 XWs[4 * 64 * 32];   // 16KB bf16 LN'd window [e][n][cc]
  __shared__ __align__(16) u16 Bs0[4 * 64 * 32];   // 16KB stage
  __shared__ __align__(16) u16 Bs1[4 * 64 * 32];   // 16KB stage
  __shared__ __align__(16) u32 Ps[4 * 32 * 64];    // 32KB P packed [h][m2][n]
  float* H1 = (float*)Ps;                          // 32KB alias after attention

  const int t = threadIdx.x;
  const int win = blockIdx.x;
  const int ihh = win / 24, iww = win % 24;
  const float SC = 0.17677669529663687f;           // 32^-0.5

  // ---------- gather + LN1 -> XWs (bf16) ----------
  {
    const int e = t >> 6, n = t & 63;
    const int cch = n >> 1, hf = n & 1;
    const float* base = X + (e * 32 + cch) * 36864 + (ihh * 8) * 192 + iww * 8;
    float v[32];
    #pragma unroll
    for (int r = 0; r < 4; ++r){
      const float4* p4 = (const float4*)(base + (hf * 4 + r) * 192);
      float4 a = p4[0], b = p4[1];
      v[r*8+0]=a.x; v[r*8+1]=a.y; v[r*8+2]=a.z; v[r*8+3]=a.w;
      v[r*8+4]=b.x; v[r*8+5]=b.y; v[r*8+6]=b.z; v[r*8+7]=b.w;
    }
    float s = 0.f;
    #pragma unroll
    for (int i = 0; i < 32; ++i) s += v[i];
    const float mean = s * 0.03125f;
    float vs = 0.f;
    #pragma unroll
    for (int i = 0; i < 32; ++i){ const float d = v[i] - mean; vs = fmaf(d, d, vs); }
    const float rstd = rsqrtf(vs * 0.03125f + 1e-5f);
    u16* dst = XWs + (e << 11) + (n << 5);
    #pragma unroll
    for (int i = 0; i < 32; ++i) dst[i] = f2b((v[i] - mean) * rstd * g1[i] + b1[i]);
  }
  __syncthreads();

  float acc11[32], acc12[32];
  #pragma unroll
  for (int i = 0; i < 32; ++i){ acc11[i] = 0.f; acc12[i] = 0.f; }

  // ---------- SA scores (accumulate 4 exposure chunks), xw WITHOUT POS ----------
  {
    float sc[64];
    #pragma unroll
    for (int m = 0; m < 64; ++m) sc[m] = 0.f;
    for (int e = 0; e < 4; ++e){
      proj(Bs0, XWs, e, Wsa, 0,   SC,  t);   // q chunk (scale folded)
      proj(Bs1, XWs, e, Wsa, 128, 1.f, t);   // k chunk
      __syncthreads();
      float qr[32];
      load_row(Bs0, t, qr);
      score_regq<true>(qr, Bs1, sc, t);
      __syncthreads();                        // reads done before next proj overwrites
    }
    {  // swin relative-position bias: rpb[((dy+7)*15 + dx+7)*4 + h]
      const int h = t >> 6, n = t & 63;
      const int by = (n >> 3) + 7, bx = (n & 7) + 7;
      #pragma unroll
      for (int m = 0; m < 64; ++m){
        const int idx = (by - (m >> 3)) * 15 + (bx - (m & 7));
        sc[m] += rpb[idx * 4 + h];
      }
    }
    softmax_P(sc, Ps, t);                     // sc dead after this
  }
  // SA PV + streamed MLP (P persists across the 4 v-chunks)
  for (int e = 0; e < 4; ++e){
    proj(Bs1, XWs, e, Wsa, 256, 1.f, t);      // v chunk
    __syncthreads();
    pv_lds(Ps, Bs1, Bs0, t);                  // OC -> Bs0 (q long dead)
    __syncthreads();
    mlp_acc(Bs0, (e << 5), W11, W12, acc11, acc12, t);   // feat rows h*128 + e*32 + k
    __syncthreads();
  }

  // ---------- XW += POS (DETR sine enc, on the fly; bf16 rmw) ----------
  {
    const int n = t & 63;
    const int e = t >> 6;
    const float ye = (float)((n >> 3) + 1) * 0.7853980652f;  // 2*pi/(8+1e-6)
    const float xe = (float)((n & 7) + 1) * 0.7853980652f;
    u16* row = XWs + (e << 11) + (n << 5);
    #pragma unroll
    for (int cc = 0; cc < 32; ++cc){
      const int j = (cc & 15) >> 1;
      const float dimv = __expf(1.1512925465f * (float)j); // 10000^(j/8)
      const float arg = ((cc < 16) ? ye : xe) / dimv;
      row[cc] = f2b(b2f(row[cc]) + ((cc & 1) ? __cosf(arg) : __sinf(arg)));
    }
  }
  __syncthreads();

  // ---------- EA1: attn(q0, k_e, v_e), feat rows 512 + h*128 + e*32 ----------
  float q0r[32];
  proj(Bs0, XWs, 0, Wea, 0, SC, t);           // q0 staged once
  __syncthreads();
  load_row(Bs0, t, q0r);                      // q0 lives in regs across the loop
  __syncthreads();                            // Bs0 free
  for (int e = 0; e < 4; ++e){
    float sc[64];
    proj(Bs1, XWs, e, Wea, 128, 1.f, t);      // k_e
    __syncthreads();
    score_regq<false>(q0r, Bs1, sc, t);
    softmax_P(sc, Ps, t);
    __syncthreads();                          // k reads done -> Bs1 reusable
    proj(Bs1, XWs, e, Wea, 256, 1.f, t);      // v_e
    __syncthreads();
    pv_lds(Ps, Bs1, Bs0, t);                  // OC -> Bs0
    __syncthreads();
    mlp_acc(Bs0, 512 + (e << 5), W11, W12, acc11, acc12, t);
    __syncthreads();
  }

  // ---------- EA2: attn(q_e, k0, v0), feat rows 1024 + h*128 + e*32 ----------
  proj(Bs1, XWs, 0, Wea, 256, 1.f, t);        // v0 persists in Bs1
  for (int e = 0; e < 4; ++e){
    float sc[64];
    proj(Bs0, XWs, 0, Wea, 128, 1.f, t);      // k0 (recomputed: OC clobbers Bs0 below)
    proj((u16*)Ps, XWs, e, Wea, 0, SC, t);    // q_e staged in (currently dead) P area
    __syncthreads();
    float qr[32];
    load_row((u16*)Ps, t, qr);
    __syncthreads();                          // all q rows in regs before P overwrite
    score_regq<false>(qr, Bs0, sc, t);
    softmax_P(sc, Ps, t);
    __syncthreads();                          // k0 reads done before OC clobbers Bs0
    pv_lds(Ps, Bs1, Bs0, t);                  // OC -> Bs0
    __syncthreads();
    mlp_acc(Bs0, 1024 + (e << 5), W11, W12, acc11, acc12, t);
    __syncthreads();
  }

  // ---------- GEGLU gate -> H1 (aliases Ps) ----------
  {
    const int n = t >> 2, jb = t & 3;
    float* h1p = H1 + n * 128 + (jb << 5);
    #pragma unroll
    for (int i = 0; i < 32; ++i){
      const float vg = acc11[i] + B11[(jb << 5) + i];
      const float vl = acc12[i] + B12[(jb << 5) + i];
      h1p[i] = gelu_ex(vg) * vl;
    }
  }
  __syncthreads();

  // ---------- fc2 + faithful un-window + residual ----------
  {
    const int n = t >> 2, db = t & 3;
    float o[32];
    #pragma unroll
    for (int i = 0; i < 32; ++i) o[i] = B2v[(db << 5) + i];
    const float* h1p = H1 + n * 128;
    for (int j = 0; j < 128; ++j){
      const float hj = h1p[j];
      const float4* wr = (const float4*)(W2 + j * 128 + (db << 5));
      #pragma unroll
      for (int q = 0; q < 8; ++q){ float4 w4 = wr[q]; FMA4A(o, 4*q, hj, w4); }
    }
    const int hh = (n >> 3) * 24 + ihh;
    const int ww = (n & 7) * 24 + iww;
    const int pix = hh * 192 + ww;
    const float* xin = X + (db << 5) * 36864 + pix;
    float* op = OUT + (db << 5) * 36864 + pix;
    #pragma unroll
    for (int i = 0; i < 32; ++i) op[i * 36864] = o[i] + xin[i * 36864];
  }
}

// ---------- K2: LN2 + GEGLU MLP2 + residual, in-place on d_out ----------
__global__ __launch_bounds__(256, 1)
void k_mlp2(float* __restrict__ IO,
            const float* __restrict__ g2, const float* __restrict__ b2,
            const float* __restrict__ W11, const float* __restrict__ B11,
            const float* __restrict__ W12, const float* __restrict__ B12,
            const float* __restrict__ W2,  const float* __restrict__ B2v)
{
  __shared__ __align__(16) float T[128 * 64];  // x1 tile [f][pix]
  __shared__ __align__(16) float U[128 * 64];  // normalized, then hidden
  const int t = threadIdx.x;
  const int p0 = blockIdx.x << 6;

  #pragma unroll
  for (int i = 0; i < 32; ++i){
    const int idx = (i << 8) + t;
    const int f = idx >> 6, pix = idx & 63;
    T[(f << 6) + pix] = IO[f * 36864 + p0 + pix];
  }
  __syncthreads();

  const int pix = t & 63, quad = t >> 6;
  {
    float sum = 0.f, ss = 0.f;
    for (int f = 0; f < 128; ++f){ const float v = T[(f << 6) + pix]; sum += v; ss = fmaf(v, v, ss); }
    const float mean = sum * 0.0078125f;
    const float var = ss * 0.0078125f - mean * mean;
    const float rstd = rsqrtf(var + 1e-5f);
    const int f0 = quad << 5;
    for (int f = f0; f < f0 + 32; ++f)
      U[(f << 6) + pix] = (T[(f << 6) + pix] - mean) * rstd * g2[f] + b2[f];
  }
  __syncthreads();

  float a1[32], a2[32];
  #pragma unroll
  for (int i = 0; i < 32; ++i){ a1[i] = 0.f; a2[i] = 0.f; }
  const int joff = quad << 5;
  for (int f = 0; f < 128; ++f){
    const float xv = U[(f << 6) + pix];
    const float4* w1 = (const float4*)(W11 + f * 128 + joff);
    const float4* w2 = (const float4*)(W12 + f * 128 + joff);
    #pragma unroll
    for (int q = 0; q < 8; ++q){ float4 wa = w1[q]; FMA4A(a1, 4*q, xv, wa); }
    #pragma unroll
    for (int q = 0; q < 8; ++q){ float4 wb = w2[q]; FMA4A(a2, 4*q, xv, wb); }
  }
  float hid[32];
  #pragma unroll
  for (int i = 0; i < 32; ++i)
    hid[i] = gelu_ex(a1[i] + B11[joff + i]) * (a2[i] + B12[joff + i]);
  __syncthreads();
  #pragma unroll
  for (int i = 0; i < 32; ++i) U[((joff + i) << 6) + pix] = hid[i];
  __syncthreads();

  float o[32];
  #pragma unroll
  for (int i = 0; i < 32; ++i) o[i] = B2v[joff + i];
  for (int j = 0; j < 128; ++j){
    const float u = U[(j << 6) + pix];
    const float4* wr = (const float4*)(W2 + j * 128 + joff);
    #pragma unroll
    for (int q = 0; q < 8; ++q){ float4 w4 = wr[q]; FMA4A(o, 4*q, u, w4); }
  }
  #pragma unroll
  for (int i = 0; i < 32; ++i){
    const int f = joff + i;
    IO[f * 36864 + p0 + pix] = T[(f << 6) + pix] + o[i];
  }
}

extern "C" void kernel_launch(void* const* d_in, const int* in_sizes, int n_in,
                              void* d_out, int out_size, void* d_ws, size_t ws_size,
                              hipStream_t stream)
{
  (void)in_sizes; (void)n_in; (void)out_size; (void)d_ws; (void)ws_size;
  const float* X    = (const float*)d_in[0];
  const float* Wea  = (const float*)d_in[1];
  const float* Wsa  = (const float*)d_in[2];
  const float* g1   = (const float*)d_in[3];
  const float* b1   = (const float*)d_in[4];
  const float* g2   = (const float*)d_in[5];
  const float* b2   = (const float*)d_in[6];
  const float* rpb  = (const float*)d_in[7];
  const float* W11  = (const float*)d_in[8];
  const float* B11  = (const float*)d_in[9];
  const float* W12  = (const float*)d_in[10];
  const float* B12  = (const float*)d_in[11];
  const float* W2   = (const float*)d_in[12];
  const float* B2v  = (const float*)d_in[13];
  const float* m11  = (const float*)d_in[14];
  const float* mb11 = (const float*)d_in[15];
  const float* m12  = (const float*)d_in[16];
  const float* mb12 = (const float*)d_in[17];
  const float* m2w  = (const float*)d_in[18];
  const float* mb2  = (const float*)d_in[19];
  float* OUT = (float*)d_out;

  k_win<<<dim3(576), dim3(256), 0, stream>>>(X, Wea, Wsa, g1, b1, rpb,
                                             W11, B11, W12, B12, W2, B2v, OUT);
  k_mlp2<<<dim3(576), dim3(256), 0, stream>>>(OUT, g2, b2, m11, mb11, m12, mb12, m2w, mb2);
}

// Round 5
// 7493.041 us; speedup vs baseline: 1.3895x; 1.3339x over previous
//
#include <hip/hip_runtime.h>
#include <math.h>

// SRHDR fused windowed-attention block, MI355X round 5.
// R5: 512-thread blocks to halve per-thread register state (R3/R4 proved 256-thread
// cannot fit 128 VGPR; at 256 VGPR only 1 wave/SIMD). All phases re-mapped:
//  - scores: wave (h, m-half), lane n, sc[32]; softmax joined via 4KB LDS reduce
//  - PV: wave (h, c-half), o[16]
//  - MLP1: acc 16+16 per thread (j split 8 ways)
// Target: <=128 VGPR, LDS 80KB -> 2 blocks/CU = 16 waves/CU.

typedef unsigned short u16;
typedef unsigned int u32;

#define DEVINL __device__ __forceinline__

DEVINL float blo(u32 u){ return __uint_as_float(u << 16); }
DEVINL float bhi(u32 u){ return __uint_as_float(u & 0xffff0000u); }
DEVINL float b2f(u16 h){ return __uint_as_float(((u32)h) << 16); }
DEVINL u16 f2b(float f){
  u32 u = __float_as_uint(f);
  return (u16)((u + 0x7fffu + ((u >> 16) & 1u)) >> 16);   // RNE
}
DEVINL float gelu_ex(float x){ return 0.5f * x * (1.0f + erff(x * 0.7071067811865476f)); }

#define UNP8(q, B, u) \
  q[(B)+0]=blo(u.x); q[(B)+1]=bhi(u.x); q[(B)+2]=blo(u.y); q[(B)+3]=bhi(u.y); \
  q[(B)+4]=blo(u.z); q[(B)+5]=bhi(u.z); q[(B)+6]=blo(u.w); q[(B)+7]=bhi(u.w);

#define DOT8(a, u, q, B) \
  a = fmaf(q[(B)+0], blo(u.x), a); a = fmaf(q[(B)+1], bhi(u.x), a); \
  a = fmaf(q[(B)+2], blo(u.y), a); a = fmaf(q[(B)+3], bhi(u.y), a); \
  a = fmaf(q[(B)+4], blo(u.z), a); a = fmaf(q[(B)+5], bhi(u.z), a); \
  a = fmaf(q[(B)+6], blo(u.w), a); a = fmaf(q[(B)+7], bhi(u.w), a);

#define AXPY8(o, B, pm, u) \
  o[(B)+0] = fmaf(pm, blo(u.x), o[(B)+0]); o[(B)+1] = fmaf(pm, bhi(u.x), o[(B)+1]); \
  o[(B)+2] = fmaf(pm, blo(u.y), o[(B)+2]); o[(B)+3] = fmaf(pm, bhi(u.y), o[(B)+3]); \
  o[(B)+4] = fmaf(pm, blo(u.z), o[(B)+4]); o[(B)+5] = fmaf(pm, bhi(u.z), o[(B)+5]); \
  o[(B)+6] = fmaf(pm, blo(u.w), o[(B)+6]); o[(B)+7] = fmaf(pm, bhi(u.w), o[(B)+7]);

// NOTE: param named W (capital) — member access .w must not collide with a macro param.
#define FMA4A(acc, B, a, W) \
  acc[(B)+0] = fmaf(a, W.x, acc[(B)+0]); acc[(B)+1] = fmaf(a, W.y, acc[(B)+1]); \
  acc[(B)+2] = fmaf(a, W.z, acc[(B)+2]); acc[(B)+3] = fmaf(a, W.w, acc[(B)+3]);

// projection (512 thr): dst[h][n][c] = sum_k XWb[e][n][k]*Wg[k][colbase+h*32+c]*scale
// map: h = t>>7, c = t&31, nq = (t>>5)&3 -> 16 n's per thread
DEVINL void proj(u16* __restrict__ dst, const u16* __restrict__ XWb, int e,
                 const float* __restrict__ Wg, int colbase, float scale, int t)
{
  const int h = t >> 7, c = t & 31, nq = (t >> 5) & 3;
  const int col = colbase + (h << 5) + c;
  float wr[32];
  #pragma unroll
  for (int k = 0; k < 32; ++k) wr[k] = Wg[k * 384 + col] * scale;
  const u16* src = XWb + (e << 11);
  u16* d = dst + (h << 11) + c;
  const int n0 = nq << 4;
  #pragma unroll 4
  for (int ni = 0; ni < 16; ++ni){
    const int n = n0 + ni;
    const uint4* row = (const uint4*)(src + (n << 5));
    uint4 u0 = row[0], u1 = row[1], u2 = row[2], u3 = row[3];
    float a = 0.f;
    DOT8(a, u0, wr, 0); DOT8(a, u1, wr, 8); DOT8(a, u2, wr, 16); DOT8(a, u3, wr, 24);
    d[n << 5] = f2b(a);
  }
}

// load (h = t>>7, n = t&63) 32-wide bf16 row into f32 regs
DEVINL void load_row(const u16* __restrict__ buf, int t, float q[32]){
  const int h = t >> 7, n = t & 63;
  const uint4* r = (const uint4*)(buf + (h << 11) + (n << 5));
  uint4 u0 = r[0], u1 = r[1], u2 = r[2], u3 = r[3];
  UNP8(q, 0, u0); UNP8(q, 8, u1); UNP8(q, 16, u2); UNP8(q, 24, u3);
}

// scores (half): wave w: h = w>>1, mh = w&1; lane n. sc[j] for m = mh*32+j.
template<bool ACC>
DEVINL void score_half(const float* __restrict__ q, const u16* __restrict__ kb,
                       float* sc, int t)
{
  const int w = t >> 6, h = w >> 1, mh = w & 1;
  const u16* kbase = kb + (h << 11) + (mh << 10);
  #pragma unroll 8
  for (int j = 0; j < 32; ++j){
    const uint4* kr = (const uint4*)(kbase + (j << 5));
    uint4 u0 = kr[0], u1 = kr[1], u2 = kr[2], u3 = kr[3];
    float a = 0.f;
    DOT8(a, u0, q, 0); DOT8(a, u1, q, 8); DOT8(a, u2, q, 16); DOT8(a, u3, q, 24);
    if (ACC) sc[j] += a; else sc[j] = a;
  }
}

// cross-half softmax: sc[32] local half; RED = 4KB f32 scratch (1024 entries used).
// returns 1/sum; leaves exp(sc-gmax) in sc.
DEVINL float softmax_red(float* sc, int t, float* __restrict__ RED){
  const int w = t >> 6, h = w >> 1, mh = w & 1, n = t & 63;
  float mx = sc[0];
  #pragma unroll
  for (int j = 1; j < 32; ++j) mx = fmaxf(mx, sc[j]);
  RED[((h << 1) + mh) * 64 + n] = mx;
  __syncthreads();
  const float gmx = fmaxf(mx, RED[((h << 1) + (mh ^ 1)) * 64 + n]);
  float sum = 0.f;
  #pragma unroll
  for (int j = 0; j < 32; ++j){ const float p = __expf(sc[j] - gmx); sc[j] = p; sum += p; }
  RED[512 + ((h << 1) + mh) * 64 + n] = sum;
  __syncthreads();
  const float osum = RED[512 + ((h << 1) + (mh ^ 1)) * 64 + n];
  return 1.f / (sum + osum);
}

// write P packed pairs: Ps[h][m2][n], m2 = global m>>1; this thread covers m2 in mh half.
DEVINL void write_P(const float* sc, float rinv, u32* __restrict__ Ps, int t){
  const int w = t >> 6, h = w >> 1, mh = w & 1, n = t & 63;
  u32* pb = Ps + (h << 11) + n;
  #pragma unroll
  for (int i = 0; i < 16; ++i){
    const int m2 = (mh << 4) + i;
    const u32 lo = f2b(sc[2*i]   * rinv);
    const u32 hi = f2b(sc[2*i+1] * rinv);
    pb[m2 << 6] = lo | (hi << 16);
  }
}

// PV (half-c): wave w: h = w>>1, ch = w&1; lane n. o[i] for c = ch*16+i.
// store TRANSPOSED oc[h][c][n].
DEVINL void pv_half(const u32* __restrict__ Ps, const u16* __restrict__ vb,
                    u16* __restrict__ oc, int t)
{
  const int w = t >> 6, h = w >> 1, ch = w & 1, n = t & 63;
  float o[16];
  #pragma unroll
  for (int i = 0; i < 16; ++i) o[i] = 0.f;
  const u16* vbase = vb + (h << 11) + (ch << 4);
  const u32* pb = Ps + (h << 11) + n;
  #pragma unroll 8
  for (int m2 = 0; m2 < 32; ++m2){
    const u32 pp = pb[m2 << 6];
    const float p0 = blo(pp), p1 = bhi(pp);
    const uint4* v0r = (const uint4*)(vbase + ((2*m2) << 5));
    const uint4* v1r = (const uint4*)(vbase + ((2*m2+1) << 5));
    uint4 a0 = v0r[0], a1 = v0r[1];
    AXPY8(o, 0, p0, a0); AXPY8(o, 8, p0, a1);
    uint4 b0 = v1r[0], b1 = v1r[1];
    AXPY8(o, 0, p1, b0); AXPY8(o, 8, p1, b1);
  }
  u16* ob = oc + (h << 11) + (((ch << 4)) << 6) + n;
  #pragma unroll
  for (int i = 0; i < 16; ++i) ob[i << 6] = f2b(o[i]);
}

// streamed MLP1: acc[n][j] += oc[h4][k][n] * W[rowbase + h4*128 + k][j]
// map: n = t>>3, jb = t&7 (16 j's each)
DEVINL void mlp_acc_f(const u16* __restrict__ oc, int rowbase,
                      const float* __restrict__ W1, const float* __restrict__ W2g,
                      float* a1, float* a2, int t)
{
  const int n = t >> 3, jb = t & 7;
  const int joff = jb << 4;
  for (int h4 = 0; h4 < 4; ++h4){
    const u16* op = oc + (h4 << 11) + n;
    const float* w1b = W1  + (rowbase + (h4 << 7)) * 128 + joff;
    const float* w2b = W2g + (rowbase + (h4 << 7)) * 128 + joff;
    for (int k = 0; k < 32; ++k){
      const float a = b2f(op[k << 6]);
      const float4* w1 = (const float4*)(w1b + k * 128);
      const float4* w2 = (const float4*)(w2b + k * 128);
      #pragma unroll
      for (int q = 0; q < 4; ++q){ float4 wa = w1[q]; FMA4A(a1, 4*q, a, wa); }
      #pragma unroll
      for (int q = 0; q < 4; ++q){ float4 wb = w2[q]; FMA4A(a2, 4*q, a, wb); }
    }
  }
}

__global__ __launch_bounds__(512, 4)
void k_win(const float* __restrict__ X,
           const float* __restrict__ Wea, const float* __restrict__ Wsa,
           const float* __restrict__ g1, const float* __restrict__ b1,
           const float* __restrict__ rpb,
           const float* __restrict__ W11, const float* __restrict__ B11,
           const float* __restrict__ W12, const float* __restrict__ B12,
           const float* __restrict__ W2,  const float* __restrict__ B2v,
           float* __restrict__ OUT)
{
  __shared__ __align__(16) u16 XWs[4 * 64 * 32];   // 16KB bf16 LN'd window [e][n][cc]
  __shared__ __align__(16) u16 Bs0[4 * 64 * 32];   // 16KB stage (k / OC / RED scratch)
  __shared__ __align__(16) u16 Bs1[4 * 64 * 32];   // 16KB stage (v)
  __shared__ __align__(16) u32 Ps[4 * 32 * 64];    // 32KB P packed / q stage / H1 alias
  float* H1 = (float*)Ps;                          // [j][n] transposed, 32KB
  float* RED = (float*)Bs0;                        // 4KB softmax reduce scratch

  const int t = threadIdx.x;
  const int win = blockIdx.x;
  const int ihh = win / 24, iww = win % 24;
  const float SC = 0.17677669529663687f;           // 32^-0.5

  // ---------- gather + LN1 -> XWs (bf16); 2 threads per row ----------
  {
    const int row = t >> 1, th = t & 1;
    const int e = row >> 6, n = row & 63;
    const int cch = n >> 1, hf = n & 1;
    const float* base = X + (e * 32 + cch) * 36864 + (ihh * 8) * 192 + iww * 8;
    float v[16];
    #pragma unroll
    for (int rr = 0; rr < 2; ++rr){
      const float4* p4 = (const float4*)(base + (hf * 4 + th * 2 + rr) * 192);
      float4 a = p4[0], b = p4[1];
      v[rr*8+0]=a.x; v[rr*8+1]=a.y; v[rr*8+2]=a.z; v[rr*8+3]=a.w;
      v[rr*8+4]=b.x; v[rr*8+5]=b.y; v[rr*8+6]=b.z; v[rr*8+7]=b.w;
    }
    float s = 0.f;
    #pragma unroll
    for (int i = 0; i < 16; ++i) s += v[i];
    s += __shfl_xor(s, 1);
    const float mean = s * 0.03125f;
    float vs = 0.f;
    #pragma unroll
    for (int i = 0; i < 16; ++i){ const float d = v[i] - mean; vs = fmaf(d, d, vs); }
    vs += __shfl_xor(vs, 1);
    const float rstd = rsqrtf(vs * 0.03125f + 1e-5f);
    u16* dst = XWs + (e << 11) + (n << 5) + (th << 4);
    #pragma unroll
    for (int i = 0; i < 16; ++i){
      const int cc = (th << 4) + i;
      dst[i] = f2b((v[i] - mean) * rstd * g1[cc] + b1[cc]);
    }
  }
  __syncthreads();

  float acc11[16], acc12[16];
  #pragma unroll
  for (int i = 0; i < 16; ++i){ acc11[i] = 0.f; acc12[i] = 0.f; }

  // ---------- SA: scores accumulate 4 exposure chunks (xw WITHOUT POS) ----------
  {
    float sc[32];
    #pragma unroll
    for (int j = 0; j < 32; ++j) sc[j] = 0.f;
    for (int e = 0; e < 4; ++e){
      proj(Bs0, XWs, e, Wsa, 0,   SC,  t);   // q chunk (scale folded)
      proj(Bs1, XWs, e, Wsa, 128, 1.f, t);   // k chunk
      __syncthreads();
      float qr[32];
      load_row(Bs0, t, qr);
      score_half<true>(qr, Bs1, sc, t);
      __syncthreads();                        // reads done before next proj / RED
    }
    {  // swin relative-position bias: rpb[((dy+7)*15 + dx+7)*4 + h]
      const int w = t >> 6, h = w >> 1, mh = w & 1, n = t & 63;
      const int by = (n >> 3) + 7, bx = (n & 7) + 7;
      #pragma unroll
      for (int j = 0; j < 32; ++j){
        const int m = (mh << 5) + j;
        const int idx = (by - (m >> 3)) * 15 + (bx - (m & 7));
        sc[j] += rpb[idx * 4 + h];
      }
    }
    const float rinv = softmax_red(sc, t, RED);
    write_P(sc, rinv, Ps, t);
  }
  __syncthreads();
  // SA PV + streamed MLP (P persists across the 4 v-chunks)
  for (int e = 0; e < 4; ++e){
    proj(Bs1, XWs, e, Wsa, 256, 1.f, t);      // v chunk
    __syncthreads();
    pv_half(Ps, Bs1, Bs0, t);                 // OC -> Bs0
    __syncthreads();
    mlp_acc_f(Bs0, (e << 5), W11, W12, acc11, acc12, t);
    __syncthreads();
  }

  // ---------- XW += POS (DETR sine enc, on the fly; bf16 rmw) ----------
  {
    const int row = t >> 1, th = t & 1;
    const int e = row >> 6, n = row & 63;
    const float ye = (float)((n >> 3) + 1) * 0.7853980652f;  // 2*pi/(8+1e-6)
    const float xe = (float)((n & 7) + 1) * 0.7853980652f;
    u16* urow = XWs + (e << 11) + (n << 5) + (th << 4);
    #pragma unroll
    for (int i = 0; i < 16; ++i){
      const int cc = (th << 4) + i;
      const int j = (cc & 15) >> 1;
      const float dimv = __expf(1.1512925465f * (float)j); // 10000^(j/8)
      const float arg = ((cc < 16) ? ye : xe) / dimv;
      urow[i] = f2b(b2f(urow[i]) + ((cc & 1) ? __cosf(arg) : __sinf(arg)));
    }
  }
  __syncthreads();

  // ---------- EA1: attn(q0, k_e, v_e), feat rows 512 + h*128 + e*32 ----------
  for (int e = 0; e < 4; ++e){
    proj((u16*)Ps, XWs, 0, Wea, 0, SC, t);    // q0 staged in (dead) P area
    proj(Bs0, XWs, e, Wea, 128, 1.f, t);      // k_e
    proj(Bs1, XWs, e, Wea, 256, 1.f, t);      // v_e
    __syncthreads();
    float qr[32];
    load_row((u16*)Ps, t, qr);
    float sc[32];
    score_half<false>(qr, Bs0, sc, t);
    __syncthreads();                          // q/k reads done before RED/P writes
    const float rinv = softmax_red(sc, t, RED);
    write_P(sc, rinv, Ps, t);
    __syncthreads();
    pv_half(Ps, Bs1, Bs0, t);                 // OC -> Bs0
    __syncthreads();
    mlp_acc_f(Bs0, 512 + (e << 5), W11, W12, acc11, acc12, t);
    __syncthreads();
  }

  // ---------- EA2: attn(q_e, k0, v0), feat rows 1024 + h*128 + e*32 ----------
  proj(Bs1, XWs, 0, Wea, 256, 1.f, t);        // v0 persists in Bs1
  for (int e = 0; e < 4; ++e){
    proj((u16*)Ps, XWs, e, Wea, 0, SC, t);    // q_e staged
    proj(Bs0, XWs, 0, Wea, 128, 1.f, t);      // k0 (re-projected: OC clobbers Bs0)
    __syncthreads();
    float qr[32];
    load_row((u16*)Ps, t, qr);
    float sc[32];
    score_half<false>(qr, Bs0, sc, t);
    __syncthreads();
    const float rinv = softmax_red(sc, t, RED);
    write_P(sc, rinv, Ps, t);
    __syncthreads();
    pv_half(Ps, Bs1, Bs0, t);                 // OC -> Bs0
    __syncthreads();
    mlp_acc_f(Bs0, 1024 + (e << 5), W11, W12, acc11, acc12, t);
    __syncthreads();
  }

  // ---------- GEGLU gate -> H1 transposed [j][n] (aliases Ps) ----------
  {
    const int n = t >> 3, jb = t & 7;
    #pragma unroll
    for (int i = 0; i < 16; ++i){
      const int j = (jb << 4) + i;
      const float vg = acc11[i] + B11[j];
      const float vl = acc12[i] + B12[j];
      H1[(j << 6) + n] = gelu_ex(vg) * vl;
    }
  }
  __syncthreads();

  // ---------- fc2 + faithful un-window + residual ----------
  {
    const int n = t >> 3, db = t & 7;
    float o[16];
    #pragma unroll
    for (int i = 0; i < 16; ++i) o[i] = B2v[(db << 4) + i];
    for (int j = 0; j < 128; ++j){
      const float hj = H1[(j << 6) + n];
      const float4* wr = (const float4*)(W2 + j * 128 + (db << 4));
      #pragma unroll
      for (int q = 0; q < 4; ++q){ float4 w4 = wr[q]; FMA4A(o, 4*q, hj, w4); }
    }
    const int hh = (n >> 3) * 24 + ihh;
    const int ww = (n & 7) * 24 + iww;
    const int pix = hh * 192 + ww;
    #pragma unroll
    for (int i = 0; i < 16; ++i){
      const int d = (db << 4) + i;                // d = e*32 + c directly
      OUT[d * 36864 + pix] = o[i] + X[d * 36864 + pix];
    }
  }
}

// ---------- K2: LN2 + GEGLU MLP2 + residual, in-place on d_out (512 thr) ----------
__global__ __launch_bounds__(512, 4)
void k_mlp2(float* __restrict__ IO,
            const float* __restrict__ g2, const float* __restrict__ b2,
            const float* __restrict__ W11, const float* __restrict__ B11,
            const float* __restrict__ W12, const float* __restrict__ B12,
            const float* __restrict__ W2,  const float* __restrict__ B2v)
{
  __shared__ __align__(16) float T[128 * 64];  // x1 tile [f][pix]
  __shared__ __align__(16) float U[128 * 64];  // normalized, then hidden
  const int t = threadIdx.x;
  const int p0 = blockIdx.x << 6;

  #pragma unroll
  for (int i = 0; i < 16; ++i){
    const int idx = (i << 9) + t;
    T[idx] = IO[(idx >> 6) * 36864 + p0 + (idx & 63)];
  }
  __syncthreads();

  const int pix = t & 63, oct = t >> 6;
  const int joff = oct << 4;
  {
    float sum = 0.f, ss = 0.f;
    for (int f = 0; f < 128; ++f){ const float v = T[(f << 6) + pix]; sum += v; ss = fmaf(v, v, ss); }
    const float mean = sum * 0.0078125f;
    const float var = ss * 0.0078125f - mean * mean;
    const float rstd = rsqrtf(var + 1e-5f);
    for (int f = joff; f < joff + 16; ++f)
      U[(f << 6) + pix] = (T[(f << 6) + pix] - mean) * rstd * g2[f] + b2[f];
  }
  __syncthreads();

  float a1[16], a2[16];
  #pragma unroll
  for (int i = 0; i < 16; ++i){ a1[i] = 0.f; a2[i] = 0.f; }
  for (int f = 0; f < 128; ++f){
    const float xv = U[(f << 6) + pix];
    const float4* w1 = (const float4*)(W11 + f * 128 + joff);
    const float4* w2 = (const float4*)(W12 + f * 128 + joff);
    #pragma unroll
    for (int q = 0; q < 4; ++q){ float4 wa = w1[q]; FMA4A(a1, 4*q, xv, wa); }
    #pragma unroll
    for (int q = 0; q < 4; ++q){ float4 wb = w2[q]; FMA4A(a2, 4*q, xv, wb); }
  }
  float hid[16];
  #pragma unroll
  for (int i = 0; i < 16; ++i)
    hid[i] = gelu_ex(a1[i] + B11[joff + i]) * (a2[i] + B12[joff + i]);
  __syncthreads();
  #pragma unroll
  for (int i = 0; i < 16; ++i) U[((joff + i) << 6) + pix] = hid[i];
  __syncthreads();

  float o[16];
  #pragma unroll
  for (int i = 0; i < 16; ++i) o[i] = B2v[joff + i];
  for (int j = 0; j < 128; ++j){
    const float u = U[(j << 6) + pix];
    const float4* wr = (const float4*)(W2 + j * 128 + joff);
    #pragma unroll
    for (int q = 0; q < 4; ++q){ float4 w4 = wr[q]; FMA4A(o, 4*q, u, w4); }
  }
  #pragma unroll
  for (int i = 0; i < 16; ++i){
    const int f = joff + i;
    IO[f * 36864 + p0 + pix] = T[(f << 6) + pix] + o[i];
  }
}

extern "C" void kernel_launch(void* const* d_in, const int* in_sizes, int n_in,
                              void* d_out, int out_size, void* d_ws, size_t ws_size,
                              hipStream_t stream)
{
  (void)in_sizes; (void)n_in; (void)out_size; (void)d_ws; (void)ws_size;
  const float* X    = (const float*)d_in[0];
  const float* Wea  = (const float*)d_in[1];
  const float* Wsa  = (const float*)d_in[2];
  const float* g1   = (const float*)d_in[3];
  const float* b1   = (const float*)d_in[4];
  const float* g2   = (const float*)d_in[5];
  const float* b2   = (const float*)d_in[6];
  const float* rpb  = (const float*)d_in[7];
  const float* W11  = (const float*)d_in[8];
  const float* B11  = (const float*)d_in[9];
  const float* W12  = (const float*)d_in[10];
  const float* B12  = (const float*)d_in[11];
  const float* W2   = (const float*)d_in[12];
  const float* B2v  = (const float*)d_in[13];
  const float* m11  = (const float*)d_in[14];
  const float* mb11 = (const float*)d_in[15];
  const float* m12  = (const float*)d_in[16];
  const float* mb12 = (const float*)d_in[17];
  const float* m2w  = (const float*)d_in[18];
  const float* mb2  = (const float*)d_in[19];
  float* OUT = (float*)d_out;

  k_win<<<dim3(576), dim3(512), 0, stream>>>(X, Wea, Wsa, g1, b1, rpb,
                                             W11, B11, W12, B12, W2, B2v, OUT);
  k_mlp2<<<dim3(576), dim3(512), 0, stream>>>(OUT, g2, b2, m11, mb11, m12, mb12, m2w, mb2);
}

// Round 6
// 679.173 us; speedup vs baseline: 15.3297x; 11.0326x over previous
//
#include <hip/hip_runtime.h>
#include <math.h>

// SRHDR fused windowed-attention block, MI355X round 6: MFMA rewrite of k_win.
// All GEMM-shaped phases on v_mfma_f32_16x16x32_bf16 (per-wave tiles -> no per-thread
// accumulator pressure). 8 waves: wave-pair per head (role splits m-tiles) for attn;
// each wave owns 16 MLP-hidden cols (f32x4 ag[4]/al[4]). XOR-swizzled LDS tiles.
// launch_bounds(512,2): empirical VGPR cap = 256/arg2 = 128. LDS 80KB -> 2 blocks/CU.

typedef unsigned short u16;
typedef unsigned int u32;
typedef short s16;
typedef __attribute__((ext_vector_type(8))) short bh8;   // 8 bf16 (4 VGPR)
typedef __attribute__((ext_vector_type(4))) float fx4;   // C/D frag

#define DEVINL __device__ __forceinline__

DEVINL float b2f(u16 h){ return __uint_as_float(((u32)h) << 16); }
DEVINL u16 f2b(float f){
  u32 u = __float_as_uint(f);
  return (u16)((u + 0x7fffu + ((u >> 16) & 1u)) >> 16);   // RNE
}
DEVINL float gelu_ex(float x){ return 0.5f * x * (1.0f + erff(x * 0.7071067811865476f)); }

DEVINL fx4 MF(bh8 a, bh8 b, fx4 c){
  return __builtin_amdgcn_mfma_f32_16x16x32_bf16(a, b, c, 0, 0, 0);
}
DEVINL bh8 ldfrag(const u16* p){ return *(const bh8*)p; }

// LDS swizzles (u16-index domain; XOR multiples of 8 u16 = 16B, frag-read safe)
DEVINL int SW32 (int row, int k){ return (row*32  + k) ^ ((((row)>>2)&3)<<3); }
DEVINL int SW64 (int row, int k){ return (row*64  + k) ^ (((row)&7)<<3); }
DEVINL int SW128(int row, int k){ return (row*128 + k) ^ (((row)&15)<<3); }

// strided f32 weight column -> bf16 fragment: elem j = p[j*ld]*scale
DEVINL bh8 wfrag(const float* __restrict__ p, int ld, float scale){
  bh8 r;
  #pragma unroll
  for (int j = 0; j < 8; ++j) r[j] = (s16)f2b(p[j*ld] * scale);
  return r;
}

// load 2 B-frags (32 output cols) of a qkv weight section
DEVINL void ld_wb(const float* __restrict__ Wg, int colbase, float scale, bh8 wb[2], int ln){
  const int cl = ln & 15, k0 = (ln >> 4) * 8;
  #pragma unroll
  for (int nt = 0; nt < 2; ++nt)
    wb[nt] = wfrag(Wg + k0*384 + colbase + 16*nt + cl, 384, scale);
}

// full 64x32 projection: dst[tok][c] = src[tok][:] @ W (both SW32)
DEVINL void proj_full(const u16* __restrict__ src, u16* __restrict__ dst,
                      const bh8 wb[2], int ln){
  const int cl = ln & 15, k0 = (ln >> 4) * 8, r0 = (ln >> 4) * 4;
  const fx4 z = {0.f,0.f,0.f,0.f};
  #pragma unroll
  for (int mt = 0; mt < 4; ++mt){
    bh8 a = ldfrag(src + SW32(16*mt + cl, k0));
    #pragma unroll
    for (int nt = 0; nt < 2; ++nt){
      fx4 d = MF(a, wb[nt], z);
      #pragma unroll
      for (int r = 0; r < 4; ++r) dst[SW32(16*mt + r0 + r, 16*nt + cl)] = f2b(d[r]);
    }
  }
}

// V projection, stored transposed vT[c][tok] (SW64), role splits m-tiles
DEVINL void proj_vT(const u16* __restrict__ src, u16* __restrict__ vT,
                    const bh8 wb[2], int ln, int role){
  const int cl = ln & 15, k0 = (ln >> 4) * 8, r0 = (ln >> 4) * 4;
  const fx4 z = {0.f,0.f,0.f,0.f};
  #pragma unroll
  for (int mtl = 0; mtl < 2; ++mtl){
    const int mt = 2*role + mtl;
    bh8 a = ldfrag(src + SW32(16*mt + cl, k0));
    #pragma unroll
    for (int nt = 0; nt < 2; ++nt){
      fx4 d = MF(a, wb[nt], z);
      const int c = 16*nt + cl;
      #pragma unroll
      for (int r = 0; r < 4; ++r) vT[SW64(c, 16*mt + r0 + r)] = f2b(d[r]);
    }
  }
}

// scores: sacc[mtl][nt] (+)= Q[16mt..][:] @ K[16nt..][:]^T
template<bool ACC>
DEVINL void score4(const u16* __restrict__ Qs, const u16* __restrict__ Ks,
                   fx4 sacc[2][4], int ln, int role){
  const int cl = ln & 15, k0 = (ln >> 4) * 8;
  const fx4 z = {0.f,0.f,0.f,0.f};
  bh8 b[4];
  #pragma unroll
  for (int nt = 0; nt < 4; ++nt) b[nt] = ldfrag(Ks + SW32(16*nt + cl, k0));
  #pragma unroll
  for (int mtl = 0; mtl < 2; ++mtl){
    bh8 a = ldfrag(Qs + SW32(16*(2*role+mtl) + cl, k0));
    #pragma unroll
    for (int nt = 0; nt < 4; ++nt)
      sacc[mtl][nt] = ACC ? MF(a, b[nt], sacc[mtl][nt]) : MF(a, b[nt], z);
  }
}

// in-register softmax over 64 keys (16-lane shfl_xor groups), P -> Ps (SW64, bf16)
DEVINL void softmax_store(fx4 sacc[2][4], u16* __restrict__ Psh, int ln, int role){
  const int cl = ln & 15, r0 = (ln >> 4) * 4;
  #pragma unroll
  for (int mtl = 0; mtl < 2; ++mtl){
    #pragma unroll
    for (int r = 0; r < 4; ++r){
      float mx = fmaxf(fmaxf(sacc[mtl][0][r], sacc[mtl][1][r]),
                       fmaxf(sacc[mtl][2][r], sacc[mtl][3][r]));
      #pragma unroll
      for (int d = 1; d < 16; d <<= 1) mx = fmaxf(mx, __shfl_xor(mx, d));
      float s = 0.f;
      #pragma unroll
      for (int nt = 0; nt < 4; ++nt){
        const float p = __expf(sacc[mtl][nt][r] - mx);
        sacc[mtl][nt][r] = p; s += p;
      }
      #pragma unroll
      for (int d = 1; d < 16; d <<= 1) s += __shfl_xor(s, d);
      const float rinv = 1.f / s;
      const int row = 16*(2*role+mtl) + r0 + r;
      #pragma unroll
      for (int nt = 0; nt < 4; ++nt)
        Psh[SW64(row, 16*nt + cl)] = f2b(sacc[mtl][nt][r] * rinv);
    }
  }
}

// PV: OC[tok][c] = P @ V (A from Ps SW64, B from vT SW64, out SW32)
DEVINL void pv_oc(const u16* __restrict__ Psh, const u16* __restrict__ vT,
                  u16* __restrict__ OCh, int ln, int role){
  const int cl = ln & 15, k0 = (ln >> 4) * 8, r0 = (ln >> 4) * 4;
  const fx4 z = {0.f,0.f,0.f,0.f};
  #pragma unroll
  for (int mtl = 0; mtl < 2; ++mtl){
    const int mt = 2*role + mtl;
    bh8 a0 = ldfrag(Psh + SW64(16*mt + cl, k0));
    bh8 a1 = ldfrag(Psh + SW64(16*mt + cl, 32 + k0));
    #pragma unroll
    for (int nt = 0; nt < 2; ++nt){
      const int c = 16*nt + cl;
      bh8 b0 = ldfrag(vT + SW64(c, k0));
      bh8 b1 = ldfrag(vT + SW64(c, 32 + k0));
      fx4 d = MF(a0, b0, z);
      d = MF(a1, b1, d);
      #pragma unroll
      for (int r = 0; r < 4; ++r) OCh[SW32(16*mt + r0 + r, c)] = f2b(d[r]);
    }
  }
}

// streamed MLP1: ag/al[mt] += OC[h4] @ W11/W12 rows (rowbase + h4*128 .. +32)
DEVINL void mlp_chunk(const u16* __restrict__ OC4, int rowbase,
                      const float* __restrict__ W11, const float* __restrict__ W12,
                      fx4 ag[4], fx4 al[4], int ln, int col0){
  const int cl = ln & 15, k0 = (ln >> 4) * 8;
  const int col = col0 + cl;
  #pragma unroll
  for (int h4 = 0; h4 < 4; ++h4){
    bh8 bg = wfrag(W11 + (rowbase + h4*128 + k0)*128 + col, 128, 1.f);
    bh8 bl = wfrag(W12 + (rowbase + h4*128 + k0)*128 + col, 128, 1.f);
    const u16* oc = OC4 + h4*2048;
    #pragma unroll
    for (int mt = 0; mt < 4; ++mt){
      bh8 a = ldfrag(oc + SW32(16*mt + cl, k0));
      ag[mt] = MF(a, bg, ag[mt]);
      al[mt] = MF(a, bl, al[mt]);
    }
  }
}

__global__ __launch_bounds__(512, 2)
void k_win(const float* __restrict__ X,
           const float* __restrict__ Wea, const float* __restrict__ Wsa,
           const float* __restrict__ g1, const float* __restrict__ b1,
           const float* __restrict__ rpb,
           const float* __restrict__ W11, const float* __restrict__ B11,
           const float* __restrict__ W12, const float* __restrict__ B12,
           const float* __restrict__ W2,  const float* __restrict__ B2v,
           float* __restrict__ OUT)
{
  __shared__ __align__(16) u16 XWs [4*64*32];  // 16KB LN'd window (bf16, SW32)
  __shared__ __align__(16) u16 BufA[4*64*32];  // 16KB Q / OC / H1
  __shared__ __align__(16) u16 BufB[4*64*32];  // 16KB K / vT
  __shared__ __align__(16) u16 Ps  [4*64*64];  // 32KB P per head (SW64)

  const int t = threadIdx.x, ln = t & 63, wv = t >> 6;
  const int h = wv >> 1, role = wv & 1;
  const int col0 = wv << 4;
  const int win = blockIdx.x;
  const int ihh = win / 24, iww = win % 24;
  const float SC = 0.17677669529663687f;       // 32^-0.5

  u16* Qs  = BufA + h*2048;
  u16* Ks  = BufB + h*2048;
  u16* Psh = Ps + h*4096;

  // ---------- gather + LN1 -> XWs ----------
  {
    const int row = t >> 1, th = t & 1;
    const int e = row >> 6, n = row & 63;
    const int cch = n >> 1, hf = n & 1;
    const float* base = X + (e * 32 + cch) * 36864 + (ihh * 8) * 192 + iww * 8;
    float v[16];
    #pragma unroll
    for (int rr = 0; rr < 2; ++rr){
      const float4* p4 = (const float4*)(base + (hf * 4 + th * 2 + rr) * 192);
      float4 a = p4[0], b = p4[1];
      v[rr*8+0]=a.x; v[rr*8+1]=a.y; v[rr*8+2]=a.z; v[rr*8+3]=a.w;
      v[rr*8+4]=b.x; v[rr*8+5]=b.y; v[rr*8+6]=b.z; v[rr*8+7]=b.w;
    }
    float s = 0.f;
    #pragma unroll
    for (int i = 0; i < 16; ++i) s += v[i];
    s += __shfl_xor(s, 1);
    const float mean = s * 0.03125f;
    float vs = 0.f;
    #pragma unroll
    for (int i = 0; i < 16; ++i){ const float d = v[i] - mean; vs = fmaf(d, d, vs); }
    vs += __shfl_xor(vs, 1);
    const float rstd = rsqrtf(vs * 0.03125f + 1e-5f);
    #pragma unroll
    for (int i = 0; i < 16; ++i){
      const int cc = (th << 4) + i;
      XWs[e*2048 + SW32(n, cc)] = f2b((v[i] - mean) * rstd * g1[cc] + b1[cc]);
    }
  }
  __syncthreads();

  fx4 ag[4], al[4];
  #pragma unroll
  for (int i = 0; i < 4; ++i){ ag[i] = (fx4){0,0,0,0}; al[i] = (fx4){0,0,0,0}; }

  // ================= SA (xw WITHOUT POS) =================
  {
    bh8 wq[2], wk[2], wvv[2];
    ld_wb(Wsa, h*32,        SC,  wq,  ln);
    ld_wb(Wsa, 128 + h*32, 1.f,  wk,  ln);
    ld_wb(Wsa, 256 + h*32, 1.f,  wvv, ln);
    fx4 sacc[2][4];
    #pragma unroll
    for (int i = 0; i < 2; ++i)
      #pragma unroll
      for (int j = 0; j < 4; ++j) sacc[i][j] = (fx4){0,0,0,0};
    for (int e = 0; e < 4; ++e){
      if (role == 0) proj_full(XWs + e*2048, Qs, wq, ln);
      else           proj_full(XWs + e*2048, Ks, wk, ln);
      __syncthreads();
      score4<true>(Qs, Ks, sacc, ln, role);
      __syncthreads();
    }
    { // swin relative-position bias
      const int cl = ln & 15, r0 = (ln >> 4) * 4;
      #pragma unroll
      for (int mtl = 0; mtl < 2; ++mtl)
        #pragma unroll
        for (int nt = 0; nt < 4; ++nt)
          #pragma unroll
          for (int r = 0; r < 4; ++r){
            const int q = 16*(2*role+mtl) + r0 + r, m = 16*nt + cl;
            const int idx = ((q>>3) - (m>>3) + 7) * 15 + ((q&7) - (m&7) + 7);
            sacc[mtl][nt][r] += rpb[idx*4 + h];
          }
    }
    softmax_store(sacc, Psh, ln, role);
    proj_vT(XWs + 0, Ks, wvv, ln, role);          // V_0 (BufB free: fenced after scores)
    __syncthreads();
    for (int e = 0; e < 4; ++e){
      pv_oc(Psh, Ks, Qs, ln, role);               // reads Ps+BufB, writes BufA
      __syncthreads();
      mlp_chunk(BufA, e*32, W11, W12, ag, al, ln, col0);
      if (e < 3) proj_vT(XWs + (e+1)*2048, Ks, wvv, ln, role);
      __syncthreads();
    }
  }

  // ---------- XW += POS ----------
  {
    const int row = t >> 1, th = t & 1;
    const int e = row >> 6, n = row & 63;
    const float ye = (float)((n >> 3) + 1) * 0.7853980652f;  // 2*pi/(8+1e-6)
    const float xe = (float)((n & 7) + 1) * 0.7853980652f;
    #pragma unroll
    for (int i = 0; i < 16; ++i){
      const int cc = (th << 4) + i;
      const int j = (cc & 15) >> 1;
      const float dimv = __expf(1.1512925465f * (float)j);   // 10000^(j/8)
      const float arg = ((cc < 16) ? ye : xe) / dimv;
      const int idx = e*2048 + SW32(n, cc);
      XWs[idx] = f2b(b2f(XWs[idx]) + ((cc & 1) ? __cosf(arg) : __sinf(arg)));
    }
  }
  __syncthreads();

  // ================= EA1: attn(q0, k_e, v_e) ================= / EA2: attn(q_e, k0, v0)
  {
    bh8 wq[2], wk[2], wvv[2];
    ld_wb(Wea, h*32,        SC,  wq,  ln);
    ld_wb(Wea, 128 + h*32, 1.f,  wk,  ln);
    ld_wb(Wea, 256 + h*32, 1.f,  wvv, ln);
    #pragma unroll 1
    for (int sec = 0; sec < 2; ++sec){
      const int rb0 = 512 + sec*512;
      #pragma unroll 1
      for (int e = 0; e < 4; ++e){
        const int eq = sec ? e : 0;     // q exposure
        const int ek = sec ? 0 : e;     // k/v exposure
        if (role == 0) proj_full(XWs + eq*2048, Qs, wq, ln);
        else           proj_full(XWs + ek*2048, Ks, wk, ln);
        __syncthreads();
        fx4 sacc[2][4];
        score4<false>(Qs, Ks, sacc, ln, role);
        __syncthreads();                 // K reads done -> BufB reusable
        softmax_store(sacc, Psh, ln, role);
        proj_vT(XWs + ek*2048, Ks, wvv, ln, role);
        __syncthreads();
        pv_oc(Psh, Ks, Qs, ln, role);
        __syncthreads();
        mlp_chunk(BufA, rb0 + e*32, W11, W12, ag, al, ln, col0);
        __syncthreads();
      }
    }
  }

  // ---------- GEGLU gate -> H1 (BufA, [64][128] SW128) ----------
  {
    const int cl = ln & 15, r0 = (ln >> 4) * 4;
    const int col = col0 + cl;
    const float bb11 = B11[col], bb12 = B12[col];
    u16* H1 = BufA;
    #pragma unroll
    for (int mt = 0; mt < 4; ++mt)
      #pragma unroll
      for (int r = 0; r < 4; ++r){
        const int tok = 16*mt + r0 + r;
        H1[SW128(tok, col)] = f2b(gelu_ex(ag[mt][r] + bb11) * (al[mt][r] + bb12));
      }
  }
  __syncthreads();

  // ---------- fc2 + un-window + residual ----------
  {
    const int cl = ln & 15, k0 = (ln >> 4) * 8, r0 = (ln >> 4) * 4;
    const int col = col0 + cl;                   // output feature d = e*32+c
    const u16* H1 = BufA;
    fx4 o[4];
    #pragma unroll
    for (int i = 0; i < 4; ++i) o[i] = (fx4){0,0,0,0};
    #pragma unroll
    for (int ks = 0; ks < 4; ++ks){
      bh8 bw = wfrag(W2 + (32*ks + k0)*128 + col, 128, 1.f);
      #pragma unroll
      for (int mt = 0; mt < 4; ++mt){
        bh8 a = ldfrag(H1 + SW128(16*mt + cl, 32*ks + k0));
        o[mt] = MF(a, bw, o[mt]);
      }
    }
    const float bias = B2v[col];
    #pragma unroll
    for (int mt = 0; mt < 4; ++mt)
      #pragma unroll
      for (int r = 0; r < 4; ++r){
        const int tok = 16*mt + r0 + r;
        const int pix = ((tok >> 3) * 24 + ihh) * 192 + (tok & 7) * 24 + iww;
        OUT[col * 36864 + pix] = o[mt][r] + bias + X[col * 36864 + pix];
      }
  }
}

// ---------- K2: LN2 + GEGLU MLP2 + residual, in-place on d_out (R4-proven) ----------
#define FMA4A(acc, B, a, W) \
  acc[(B)+0] = fmaf(a, W.x, acc[(B)+0]); acc[(B)+1] = fmaf(a, W.y, acc[(B)+1]); \
  acc[(B)+2] = fmaf(a, W.z, acc[(B)+2]); acc[(B)+3] = fmaf(a, W.w, acc[(B)+3]);

__global__ __launch_bounds__(256, 1)
void k_mlp2(float* __restrict__ IO,
            const float* __restrict__ g2, const float* __restrict__ b2,
            const float* __restrict__ W11, const float* __restrict__ B11,
            const float* __restrict__ W12, const float* __restrict__ B12,
            const float* __restrict__ W2,  const float* __restrict__ B2v)
{
  __shared__ __align__(16) float T[128 * 64];
  __shared__ __align__(16) float U[128 * 64];
  const int t = threadIdx.x;
  const int p0 = blockIdx.x << 6;

  #pragma unroll
  for (int i = 0; i < 32; ++i){
    const int idx = (i << 8) + t;
    const int f = idx >> 6, pix = idx & 63;
    T[(f << 6) + pix] = IO[f * 36864 + p0 + pix];
  }
  __syncthreads();

  const int pix = t & 63, quad = t >> 6;
  {
    float sum = 0.f, ss = 0.f;
    for (int f = 0; f < 128; ++f){ const float v = T[(f << 6) + pix]; sum += v; ss = fmaf(v, v, ss); }
    const float mean = sum * 0.0078125f;
    const float var = ss * 0.0078125f - mean * mean;
    const float rstd = rsqrtf(var + 1e-5f);
    const int f0 = quad << 5;
    for (int f = f0; f < f0 + 32; ++f)
      U[(f << 6) + pix] = (T[(f << 6) + pix] - mean) * rstd * g2[f] + b2[f];
  }
  __syncthreads();

  float a1[32], a2[32];
  #pragma unroll
  for (int i = 0; i < 32; ++i){ a1[i] = 0.f; a2[i] = 0.f; }
  const int joff = quad << 5;
  for (int f = 0; f < 128; ++f){
    const float xv = U[(f << 6) + pix];
    const float4* w1 = (const float4*)(W11 + f * 128 + joff);
    const float4* w2 = (const float4*)(W12 + f * 128 + joff);
    #pragma unroll
    for (int q = 0; q < 8; ++q){ float4 wa = w1[q]; FMA4A(a1, 4*q, xv, wa); }
    #pragma unroll
    for (int q = 0; q < 8; ++q){ float4 wb = w2[q]; FMA4A(a2, 4*q, xv, wb); }
  }
  float hid[32];
  #pragma unroll
  for (int i = 0; i < 32; ++i)
    hid[i] = gelu_ex(a1[i] + B11[joff + i]) * (a2[i] + B12[joff + i]);
  __syncthreads();
  #pragma unroll
  for (int i = 0; i < 32; ++i) U[((joff + i) << 6) + pix] = hid[i];
  __syncthreads();

  float o[32];
  #pragma unroll
  for (int i = 0; i < 32; ++i) o[i] = B2v[joff + i];
  for (int j = 0; j < 128; ++j){
    const float u = U[(j << 6) + pix];
    const float4* wr = (const float4*)(W2 + j * 128 + joff);
    #pragma unroll
    for (int q = 0; q < 8; ++q){ float4 w4 = wr[q]; FMA4A(o, 4*q, u, w4); }
  }
  #pragma unroll
  for (int i = 0; i < 32; ++i){
    const int f = joff + i;
    IO[f * 36864 + p0 + pix] = T[(f << 6) + pix] + o[i];
  }
}

extern "C" void kernel_launch(void* const* d_in, const int* in_sizes, int n_in,
                              void* d_out, int out_size, void* d_ws, size_t ws_size,
                              hipStream_t stream)
{
  (void)in_sizes; (void)n_in; (void)out_size; (void)d_ws; (void)ws_size;
  const float* X    = (const float*)d_in[0];
  const float* Wea  = (const float*)d_in[1];
  const float* Wsa  = (const float*)d_in[2];
  const float* g1   = (const float*)d_in[3];
  const float* b1   = (const float*)d_in[4];
  const float* g2   = (const float*)d_in[5];
  const float* b2   = (const float*)d_in[6];
  const float* rpb  = (const float*)d_in[7];
  const float* W11  = (const float*)d_in[8];
  const float* B11  = (const float*)d_in[9];
  const float* W12  = (const float*)d_in[10];
  const float* B12  = (const float*)d_in[11];
  const float* W2   = (const float*)d_in[12];
  const float* B2v  = (const float*)d_in[13];
  const float* m11  = (const float*)d_in[14];
  const float* mb11 = (const float*)d_in[15];
  const float* m12  = (const float*)d_in[16];
  const float* mb12 = (const float*)d_in[17];
  const float* m2w  = (const float*)d_in[18];
  const float* mb2  = (const float*)d_in[19];
  float* OUT = (float*)d_out;

  k_win<<<dim3(576), dim3(512), 0, stream>>>(X, Wea, Wsa, g1, b1, rpb,
                                             W11, B11, W12, B12, W2, B2v, OUT);
  k_mlp2<<<dim3(576), dim3(256), 0, stream>>>(OUT, g2, b2, m11, mb11, m12, mb12, m2w, mb2);
}

// Round 7
// 371.381 us; speedup vs baseline: 28.0347x; 1.8288x over previous
//
#include <hip/hip_runtime.h>
#include <math.h>

// SRHDR fused windowed-attention block, MI355X round 7.
// R7: (1) k_prep pre-transposes + bf16-casts ALL weights into d_ws so every MFMA
// B/A weight fragment is ONE global_load_dwordx4 (R6 was 8 strided dwords + 8 cvt
// per fragment -> latency-bound, MfmaUtil 4.7%). (2) k_mlp2 rewritten in MFMA
// (512 thr, 128-pixel tile; fc2 operand-swapped for coalesced stores).

typedef unsigned short u16;
typedef unsigned int u32;
typedef short s16;
typedef __attribute__((ext_vector_type(8))) short bh8;   // 8 bf16 (4 VGPR)
typedef __attribute__((ext_vector_type(4))) float fx4;   // C/D frag

#define DEVINL __device__ __forceinline__

// d_ws layout (u16 element offsets), total 483328 u16 = 966656 B
#define OFF_WSA 0
#define OFF_WEA 12288
#define OFF_W11 24576
#define OFF_W12 221184
#define OFF_W2  417792
#define OFF_M11 434176
#define OFF_M12 450560
#define OFF_M2  466944

DEVINL float b2f(u16 h){ return __uint_as_float(((u32)h) << 16); }
DEVINL u16 f2b(float f){
  u32 u = __float_as_uint(f);
  return (u16)((u + 0x7fffu + ((u >> 16) & 1u)) >> 16);   // RNE
}
DEVINL float gelu_ex(float x){ return 0.5f * x * (1.0f + erff(x * 0.7071067811865476f)); }

DEVINL fx4 MF(bh8 a, bh8 b, fx4 c){
  return __builtin_amdgcn_mfma_f32_16x16x32_bf16(a, b, c, 0, 0, 0);
}
DEVINL bh8 ld8(const u16* p){ return *(const bh8*)p; }

// LDS swizzles (u16-index domain; XOR multiples of 8 u16 = 16B, frag-read safe)
DEVINL int SW32 (int row, int k){ return (row*32  + k) ^ ((((row)>>2)&3)<<3); }
DEVINL int SW64 (int row, int k){ return (row*64  + k) ^ (((row)&7)<<3); }
DEVINL int SW128(int row, int k){ return (row*128 + k) ^ (((row)&15)<<3); }

// ---------------- k_prep: transpose + bf16-cast weights into ws ----------------
__global__ __launch_bounds__(256)
void k_prep(const float* __restrict__ Wsa, const float* __restrict__ Wea,
            const float* __restrict__ W11, const float* __restrict__ W12,
            const float* __restrict__ W2,  const float* __restrict__ m11,
            const float* __restrict__ m12, const float* __restrict__ m2w,
            u16* __restrict__ WS)
{
  const int tid = blockIdx.x * 256 + threadIdx.x;
  const int NT = gridDim.x * 256;
  const float SC = 0.17677669529663687f;   // 32^-0.5, folded into q cols (<128)
  for (int s = tid; s < 12288; s += NT){
    const int k = s / 384, c = s % 384;
    const float sc = (c < 128) ? SC : 1.f;
    WS[OFF_WSA + c*32 + k] = f2b(Wsa[s] * sc);
    WS[OFF_WEA + c*32 + k] = f2b(Wea[s] * sc);
  }
  for (int s = tid; s < 196608; s += NT){
    const int r = s >> 7, c = s & 127;
    WS[OFF_W11 + c*1536 + r] = f2b(W11[s]);
    WS[OFF_W12 + c*1536 + r] = f2b(W12[s]);
  }
  for (int s = tid; s < 16384; s += NT){
    const int r = s >> 7, c = s & 127;
    WS[OFF_W2  + c*128 + r] = f2b(W2 [s]);
    WS[OFF_M11 + c*128 + r] = f2b(m11[s]);
    WS[OFF_M12 + c*128 + r] = f2b(m12[s]);
    WS[OFF_M2  + c*128 + r] = f2b(m2w[s]);
  }
}

// load 2 B-frags (32 output cols) of a qkv weight section: one dwordx4 each
DEVINL void ld_wb(const u16* __restrict__ WT, int colbase, bh8 wb[2], int ln){
  const int cl = ln & 15, k0 = (ln >> 4) * 8;
  #pragma unroll
  for (int nt = 0; nt < 2; ++nt)
    wb[nt] = ld8(WT + (colbase + 16*nt + cl)*32 + k0);
}

// full 64x32 projection: dst[tok][c] = src[tok][:] @ W (both SW32)
DEVINL void proj_full(const u16* __restrict__ src, u16* __restrict__ dst,
                      const bh8 wb[2], int ln){
  const int cl = ln & 15, k0 = (ln >> 4) * 8, r0 = (ln >> 4) * 4;
  const fx4 z = {0.f,0.f,0.f,0.f};
  #pragma unroll
  for (int mt = 0; mt < 4; ++mt){
    bh8 a = ld8(src + SW32(16*mt + cl, k0));
    #pragma unroll
    for (int nt = 0; nt < 2; ++nt){
      fx4 d = MF(a, wb[nt], z);
      #pragma unroll
      for (int r = 0; r < 4; ++r) dst[SW32(16*mt + r0 + r, 16*nt + cl)] = f2b(d[r]);
    }
  }
}

// V projection, stored transposed vT[c][tok] (SW64), role splits m-tiles
DEVINL void proj_vT(const u16* __restrict__ src, u16* __restrict__ vT,
                    const bh8 wb[2], int ln, int role){
  const int cl = ln & 15, k0 = (ln >> 4) * 8, r0 = (ln >> 4) * 4;
  const fx4 z = {0.f,0.f,0.f,0.f};
  #pragma unroll
  for (int mtl = 0; mtl < 2; ++mtl){
    const int mt = 2*role + mtl;
    bh8 a = ld8(src + SW32(16*mt + cl, k0));
    #pragma unroll
    for (int nt = 0; nt < 2; ++nt){
      fx4 d = MF(a, wb[nt], z);
      const int c = 16*nt + cl;
      #pragma unroll
      for (int r = 0; r < 4; ++r) vT[SW64(c, 16*mt + r0 + r)] = f2b(d[r]);
    }
  }
}

// scores: sacc[mtl][nt] (+)= Q[16mt..][:] @ K[16nt..][:]^T
template<bool ACC>
DEVINL void score4(const u16* __restrict__ Qs, const u16* __restrict__ Ks,
                   fx4 sacc[2][4], int ln, int role){
  const int cl = ln & 15, k0 = (ln >> 4) * 8;
  const fx4 z = {0.f,0.f,0.f,0.f};
  bh8 b[4];
  #pragma unroll
  for (int nt = 0; nt < 4; ++nt) b[nt] = ld8(Ks + SW32(16*nt + cl, k0));
  #pragma unroll
  for (int mtl = 0; mtl < 2; ++mtl){
    bh8 a = ld8(Qs + SW32(16*(2*role+mtl) + cl, k0));
    #pragma unroll
    for (int nt = 0; nt < 4; ++nt)
      sacc[mtl][nt] = ACC ? MF(a, b[nt], sacc[mtl][nt]) : MF(a, b[nt], z);
  }
}

// in-register softmax over 64 keys (16-lane shfl_xor groups), P -> Ps (SW64, bf16)
DEVINL void softmax_store(fx4 sacc[2][4], u16* __restrict__ Psh, int ln, int role){
  const int cl = ln & 15, r0 = (ln >> 4) * 4;
  #pragma unroll
  for (int mtl = 0; mtl < 2; ++mtl){
    #pragma unroll
    for (int r = 0; r < 4; ++r){
      float mx = fmaxf(fmaxf(sacc[mtl][0][r], sacc[mtl][1][r]),
                       fmaxf(sacc[mtl][2][r], sacc[mtl][3][r]));
      #pragma unroll
      for (int d = 1; d < 16; d <<= 1) mx = fmaxf(mx, __shfl_xor(mx, d));
      float s = 0.f;
      #pragma unroll
      for (int nt = 0; nt < 4; ++nt){
        const float p = __expf(sacc[mtl][nt][r] - mx);
        sacc[mtl][nt][r] = p; s += p;
      }
      #pragma unroll
      for (int d = 1; d < 16; d <<= 1) s += __shfl_xor(s, d);
      const float rinv = 1.f / s;
      const int row = 16*(2*role+mtl) + r0 + r;
      #pragma unroll
      for (int nt = 0; nt < 4; ++nt)
        Psh[SW64(row, 16*nt + cl)] = f2b(sacc[mtl][nt][r] * rinv);
    }
  }
}

// PV: OC[tok][c] = P @ V (A from Ps SW64, B from vT SW64, out SW32)
DEVINL void pv_oc(const u16* __restrict__ Psh, const u16* __restrict__ vT,
                  u16* __restrict__ OCh, int ln, int role){
  const int cl = ln & 15, k0 = (ln >> 4) * 8, r0 = (ln >> 4) * 4;
  const fx4 z = {0.f,0.f,0.f,0.f};
  #pragma unroll
  for (int mtl = 0; mtl < 2; ++mtl){
    const int mt = 2*role + mtl;
    bh8 a0 = ld8(Psh + SW64(16*mt + cl, k0));
    bh8 a1 = ld8(Psh + SW64(16*mt + cl, 32 + k0));
    #pragma unroll
    for (int nt = 0; nt < 2; ++nt){
      const int c = 16*nt + cl;
      bh8 b0 = ld8(vT + SW64(c, k0));
      bh8 b1 = ld8(vT + SW64(c, 32 + k0));
      fx4 d = MF(a0, b0, z);
      d = MF(a1, b1, d);
      #pragma unroll
      for (int r = 0; r < 4; ++r) OCh[SW32(16*mt + r0 + r, c)] = f2b(d[r]);
    }
  }
}

// streamed MLP1: ag/al[mt] += OC[h4] @ W11T/W12T rows; frags are single dwordx4 loads
DEVINL void mlp_chunk(const u16* __restrict__ OC4, int rowbase,
                      const u16* __restrict__ WS,
                      fx4 ag[4], fx4 al[4], int ln, int col0){
  const int cl = ln & 15, k0 = (ln >> 4) * 8;
  const int col = col0 + cl;
  #pragma unroll
  for (int h4 = 0; h4 < 4; ++h4){
    bh8 bg = ld8(WS + OFF_W11 + col*1536 + rowbase + h4*128 + k0);
    bh8 bl = ld8(WS + OFF_W12 + col*1536 + rowbase + h4*128 + k0);
    const u16* oc = OC4 + h4*2048;
    #pragma unroll
    for (int mt = 0; mt < 4; ++mt){
      bh8 a = ld8(oc + SW32(16*mt + cl, k0));
      ag[mt] = MF(a, bg, ag[mt]);
      al[mt] = MF(a, bl, al[mt]);
    }
  }
}

__global__ __launch_bounds__(512, 2)
void k_win(const float* __restrict__ X, const u16* __restrict__ WS,
           const float* __restrict__ g1, const float* __restrict__ b1,
           const float* __restrict__ rpb,
           const float* __restrict__ B11, const float* __restrict__ B12,
           const float* __restrict__ B2v,
           float* __restrict__ OUT)
{
  __shared__ __align__(16) u16 XWs [4*64*32];  // 16KB LN'd window (bf16, SW32)
  __shared__ __align__(16) u16 BufA[4*64*32];  // 16KB Q / OC / H1
  __shared__ __align__(16) u16 BufB[4*64*32];  // 16KB K / vT
  __shared__ __align__(16) u16 Ps  [4*64*64];  // 32KB P per head (SW64)

  const int t = threadIdx.x, ln = t & 63, wv = t >> 6;
  const int h = wv >> 1, role = wv & 1;
  const int col0 = wv << 4;
  const int win = blockIdx.x;
  const int ihh = win / 24, iww = win % 24;

  u16* Qs  = BufA + h*2048;
  u16* Ks  = BufB + h*2048;
  u16* Psh = Ps + h*4096;

  // ---------- gather + LN1 -> XWs ----------
  {
    const int row = t >> 1, th = t & 1;
    const int e = row >> 6, n = row & 63;
    const int cch = n >> 1, hf = n & 1;
    const float* base = X + (e * 32 + cch) * 36864 + (ihh * 8) * 192 + iww * 8;
    float v[16];
    #pragma unroll
    for (int rr = 0; rr < 2; ++rr){
      const float4* p4 = (const float4*)(base + (hf * 4 + th * 2 + rr) * 192);
      float4 a = p4[0], b = p4[1];
      v[rr*8+0]=a.x; v[rr*8+1]=a.y; v[rr*8+2]=a.z; v[rr*8+3]=a.w;
      v[rr*8+4]=b.x; v[rr*8+5]=b.y; v[rr*8+6]=b.z; v[rr*8+7]=b.w;
    }
    float s = 0.f;
    #pragma unroll
    for (int i = 0; i < 16; ++i) s += v[i];
    s += __shfl_xor(s, 1);
    const float mean = s * 0.03125f;
    float vs = 0.f;
    #pragma unroll
    for (int i = 0; i < 16; ++i){ const float d = v[i] - mean; vs = fmaf(d, d, vs); }
    vs += __shfl_xor(vs, 1);
    const float rstd = rsqrtf(vs * 0.03125f + 1e-5f);
    #pragma unroll
    for (int i = 0; i < 16; ++i){
      const int cc = (th << 4) + i;
      XWs[e*2048 + SW32(n, cc)] = f2b((v[i] - mean) * rstd * g1[cc] + b1[cc]);
    }
  }
  __syncthreads();

  fx4 ag[4], al[4];
  #pragma unroll
  for (int i = 0; i < 4; ++i){ ag[i] = (fx4){0,0,0,0}; al[i] = (fx4){0,0,0,0}; }

  // ================= SA (xw WITHOUT POS) =================
  {
    bh8 wq[2], wk[2], wvv[2];
    ld_wb(WS + OFF_WSA, h*32,       wq,  ln);
    ld_wb(WS + OFF_WSA, 128 + h*32, wk,  ln);
    ld_wb(WS + OFF_WSA, 256 + h*32, wvv, ln);
    fx4 sacc[2][4];
    #pragma unroll
    for (int i = 0; i < 2; ++i)
      #pragma unroll
      for (int j = 0; j < 4; ++j) sacc[i][j] = (fx4){0,0,0,0};
    for (int e = 0; e < 4; ++e){
      if (role == 0) proj_full(XWs + e*2048, Qs, wq, ln);
      else           proj_full(XWs + e*2048, Ks, wk, ln);
      __syncthreads();
      score4<true>(Qs, Ks, sacc, ln, role);
      __syncthreads();
    }
    { // swin relative-position bias
      const int cl = ln & 15, r0 = (ln >> 4) * 4;
      #pragma unroll
      for (int mtl = 0; mtl < 2; ++mtl)
        #pragma unroll
        for (int nt = 0; nt < 4; ++nt)
          #pragma unroll
          for (int r = 0; r < 4; ++r){
            const int q = 16*(2*role+mtl) + r0 + r, m = 16*nt + cl;
            const int idx = ((q>>3) - (m>>3) + 7) * 15 + ((q&7) - (m&7) + 7);
            sacc[mtl][nt][r] += rpb[idx*4 + h];
          }
    }
    softmax_store(sacc, Psh, ln, role);
    proj_vT(XWs + 0, Ks, wvv, ln, role);          // V_0 (BufB free: fenced after scores)
    __syncthreads();
    for (int e = 0; e < 4; ++e){
      pv_oc(Psh, Ks, Qs, ln, role);               // reads Ps+BufB, writes BufA
      __syncthreads();
      mlp_chunk(BufA, e*32, WS, ag, al, ln, col0);
      if (e < 3) proj_vT(XWs + (e+1)*2048, Ks, wvv, ln, role);
      __syncthreads();
    }
  }

  // ---------- XW += POS ----------
  {
    const int row = t >> 1, th = t & 1;
    const int e = row >> 6, n = row & 63;
    const float ye = (float)((n >> 3) + 1) * 0.7853980652f;  // 2*pi/(8+1e-6)
    const float xe = (float)((n & 7) + 1) * 0.7853980652f;
    #pragma unroll
    for (int i = 0; i < 16; ++i){
      const int cc = (th << 4) + i;
      const int j = (cc & 15) >> 1;
      const float dimv = __expf(1.1512925465f * (float)j);   // 10000^(j/8)
      const float arg = ((cc < 16) ? ye : xe) / dimv;
      const int idx = e*2048 + SW32(n, cc);
      XWs[idx] = f2b(b2f(XWs[idx]) + ((cc & 1) ? __cosf(arg) : __sinf(arg)));
    }
  }
  __syncthreads();

  // ============ EA1: attn(q0,k_e,v_e) / EA2: attn(q_e,k0,v0) ============
  {
    bh8 wq[2], wk[2], wvv[2];
    ld_wb(WS + OFF_WEA, h*32,       wq,  ln);
    ld_wb(WS + OFF_WEA, 128 + h*32, wk,  ln);
    ld_wb(WS + OFF_WEA, 256 + h*32, wvv, ln);
    #pragma unroll 1
    for (int sec = 0; sec < 2; ++sec){
      const int rb0 = 512 + sec*512;
      #pragma unroll 1
      for (int e = 0; e < 4; ++e){
        const int eq = sec ? e : 0;     // q exposure
        const int ek = sec ? 0 : e;     // k/v exposure
        if (role == 0) proj_full(XWs + eq*2048, Qs, wq, ln);
        else           proj_full(XWs + ek*2048, Ks, wk, ln);
        __syncthreads();
        fx4 sacc[2][4];
        score4<false>(Qs, Ks, sacc, ln, role);
        __syncthreads();                 // K reads done -> BufB reusable
        softmax_store(sacc, Psh, ln, role);
        proj_vT(XWs + ek*2048, Ks, wvv, ln, role);
        __syncthreads();
        pv_oc(Psh, Ks, Qs, ln, role);
        __syncthreads();
        mlp_chunk(BufA, rb0 + e*32, WS, ag, al, ln, col0);
        __syncthreads();
      }
    }
  }

  // ---------- GEGLU gate -> H1 (BufA, [64][128] SW128) ----------
  {
    const int cl = ln & 15, r0 = (ln >> 4) * 4;
    const int col = col0 + cl;
    const float bb11 = B11[col], bb12 = B12[col];
    u16* H1 = BufA;
    #pragma unroll
    for (int mt = 0; mt < 4; ++mt)
      #pragma unroll
      for (int r = 0; r < 4; ++r){
        const int tok = 16*mt + r0 + r;
        H1[SW128(tok, col)] = f2b(gelu_ex(ag[mt][r] + bb11) * (al[mt][r] + bb12));
      }
  }
  __syncthreads();

  // ---------- fc2 + un-window + residual ----------
  {
    const int cl = ln & 15, k0 = (ln >> 4) * 8, r0 = (ln >> 4) * 4;
    const int col = col0 + cl;                   // output feature d = e*32+c
    const u16* H1 = BufA;
    fx4 o[4];
    #pragma unroll
    for (int i = 0; i < 4; ++i) o[i] = (fx4){0,0,0,0};
    #pragma unroll
    for (int ks = 0; ks < 4; ++ks){
      bh8 bw = ld8(WS + OFF_W2 + col*128 + 32*ks + k0);
      #pragma unroll
      for (int mt = 0; mt < 4; ++mt){
        bh8 a = ld8(H1 + SW128(16*mt + cl, 32*ks + k0));
        o[mt] = MF(a, bw, o[mt]);
      }
    }
    const float bias = B2v[col];
    #pragma unroll
    for (int mt = 0; mt < 4; ++mt)
      #pragma unroll
      for (int r = 0; r < 4; ++r){
        const int tok = 16*mt + r0 + r;
        const int pix = ((tok >> 3) * 24 + ihh) * 192 + (tok & 7) * 24 + iww;
        OUT[col * 36864 + pix] = o[mt][r] + bias + X[col * 36864 + pix];
      }
  }
}

// ---------- K2 (MFMA): LN2 + GEGLU MLP2 + residual, in-place, 128-pixel tiles ----------
__global__ __launch_bounds__(512, 2)
void k_mlp2(float* __restrict__ IO, const u16* __restrict__ WS,
            const float* __restrict__ g2,  const float* __restrict__ b2,
            const float* __restrict__ mb11, const float* __restrict__ mb12,
            const float* __restrict__ mb2)
{
  __shared__ __align__(16) u16 U[128*128];   // 32KB LN'd x1, [pix][f] SW128
  __shared__ __align__(16) u16 H[128*128];   // 32KB hidden (phase1 overlay: stats)
  float* SUMp = (float*)H;                   // [8][128]
  float* SSQp = (float*)(H + 2048);          // [8][128]
  float* MUp  = (float*)(H + 4096);          // [128]
  float* RSp  = (float*)(H + 4352);          // [128]

  const int t = threadIdx.x, ln = t & 63, w = t >> 6;
  const int cl = ln & 15, k0 = (ln >> 4) * 8, r0 = (ln >> 4) * 4;
  const int p0 = blockIdx.x << 7;
  const int fbase = w << 4;

  // ---- phase 1: load 16 f-rows x 128 pix per wave; per-pixel LN stats ----
  float v[2][16];
  {
    float s[2] = {0.f, 0.f}, q[2] = {0.f, 0.f};
    #pragma unroll
    for (int i = 0; i < 16; ++i){
      const float a0 = IO[(fbase + i) * 36864 + p0 + ln];
      const float a1 = IO[(fbase + i) * 36864 + p0 + 64 + ln];
      v[0][i] = a0; v[1][i] = a1;
      s[0] += a0; s[1] += a1;
      q[0] = fmaf(a0, a0, q[0]); q[1] = fmaf(a1, a1, q[1]);
    }
    SUMp[w*128 + ln]      = s[0];
    SUMp[w*128 + 64 + ln] = s[1];
    SSQp[w*128 + ln]      = q[0];
    SSQp[w*128 + 64 + ln] = q[1];
  }
  __syncthreads();
  if (t < 128){
    float su = 0.f, sq = 0.f;
    #pragma unroll
    for (int ww = 0; ww < 8; ++ww){ su += SUMp[ww*128 + t]; sq += SSQp[ww*128 + t]; }
    const float mean = su * 0.0078125f;
    const float var = sq * 0.0078125f - mean * mean;
    MUp[t] = mean;
    RSp[t] = rsqrtf(var + 1e-5f);
  }
  __syncthreads();
  {
    #pragma unroll
    for (int hf = 0; hf < 2; ++hf){
      const int pix = (hf << 6) + ln;
      const float mu = MUp[pix], rs = RSp[pix];
      #pragma unroll
      for (int i = 0; i < 16; ++i){
        const int f = fbase + i;
        U[SW128(pix, f)] = f2b((v[hf][i] - mu) * rs * g2[f] + b2[f]);
      }
    }
  }
  __syncthreads();

  // ---- phase 2: hidden = U @ m11 / m12 (wave owns 16 hidden cols) ----
  const int col = (w << 4) + cl;
  fx4 ag[8], al[8];
  #pragma unroll
  for (int i = 0; i < 8; ++i){ ag[i] = (fx4){0,0,0,0}; al[i] = (fx4){0,0,0,0}; }
  #pragma unroll
  for (int ks = 0; ks < 4; ++ks){
    bh8 bg = ld8(WS + OFF_M11 + col*128 + 32*ks + k0);
    bh8 bl = ld8(WS + OFF_M12 + col*128 + 32*ks + k0);
    #pragma unroll
    for (int mt = 0; mt < 8; ++mt){
      bh8 a = ld8(U + SW128(16*mt + cl, 32*ks + k0));
      ag[mt] = MF(a, bg, ag[mt]);
      al[mt] = MF(a, bl, al[mt]);
    }
  }
  // ---- phase 3: GEGLU -> H [pix][j] SW128 ----
  {
    const float bb1 = mb11[col], bb2 = mb12[col];
    #pragma unroll
    for (int mt = 0; mt < 8; ++mt)
      #pragma unroll
      for (int r = 0; r < 4; ++r){
        const int pix = 16*mt + r0 + r;
        H[SW128(pix, col)] = f2b(gelu_ex(ag[mt][r] + bb1) * (al[mt][r] + bb2));
      }
  }
  __syncthreads();

  // ---- phase 4: out = H @ m2 (operand-swapped: rows=features, cols=pixels) ----
  const int f0 = w << 4;
  bh8 aw[4];
  #pragma unroll
  for (int ks = 0; ks < 4; ++ks)
    aw[ks] = ld8(WS + OFF_M2 + (f0 + cl)*128 + 32*ks + k0);
  fx4 o[8];
  #pragma unroll
  for (int i = 0; i < 8; ++i) o[i] = (fx4){0,0,0,0};
  #pragma unroll
  for (int pt = 0; pt < 8; ++pt)
    #pragma unroll
    for (int ks = 0; ks < 4; ++ks){
      bh8 b = ld8(H + SW128(16*pt + cl, 32*ks + k0));
      o[pt] = MF(aw[ks], b, o[pt]);
    }

  // ---- phase 5: residual add + coalesced store (each location owned by 1 thread) ----
  #pragma unroll
  for (int pt = 0; pt < 8; ++pt)
    #pragma unroll
    for (int r = 0; r < 4; ++r){
      const int f = f0 + r0 + r;
      const int gp = f * 36864 + p0 + 16*pt + cl;
      IO[gp] = IO[gp] + o[pt][r] + mb2[f];
    }
}

extern "C" void kernel_launch(void* const* d_in, const int* in_sizes, int n_in,
                              void* d_out, int out_size, void* d_ws, size_t ws_size,
                              hipStream_t stream)
{
  (void)in_sizes; (void)n_in; (void)out_size; (void)ws_size;
  const float* X    = (const float*)d_in[0];
  const float* Wea  = (const float*)d_in[1];
  const float* Wsa  = (const float*)d_in[2];
  const float* g1   = (const float*)d_in[3];
  const float* b1   = (const float*)d_in[4];
  const float* g2   = (const float*)d_in[5];
  const float* b2   = (const float*)d_in[6];
  const float* rpb  = (const float*)d_in[7];
  const float* W11  = (const float*)d_in[8];
  const float* B11  = (const float*)d_in[9];
  const float* W12  = (const float*)d_in[10];
  const float* B12  = (const float*)d_in[11];
  const float* W2   = (const float*)d_in[12];
  const float* B2v  = (const float*)d_in[13];
  const float* m11  = (const float*)d_in[14];
  const float* mb11 = (const float*)d_in[15];
  const float* m12  = (const float*)d_in[16];
  const float* mb12 = (const float*)d_in[17];
  const float* m2w  = (const float*)d_in[18];
  const float* mb2  = (const float*)d_in[19];
  float* OUT = (float*)d_out;
  u16* WS = (u16*)d_ws;

  k_prep<<<dim3(256), dim3(256), 0, stream>>>(Wsa, Wea, W11, W12, W2, m11, m12, m2w, WS);
  k_win<<<dim3(576), dim3(512), 0, stream>>>(X, WS, g1, b1, rpb, B11, B12, B2v, OUT);
  k_mlp2<<<dim3(288), dim3(512), 0, stream>>>(OUT, WS, g2, b2, mb11, mb12, mb2);
}